// Round 1
// baseline (112719.019 us; speedup 1.0000x reference)
//
#include <hip/hip_runtime.h>

typedef short s8v __attribute__((ext_vector_type(8)));
typedef float f4v __attribute__((ext_vector_type(4)));

#define NLAYER 6
#define HID    512
#define PROJ   128
#define SEQT   512
#define BATCH  512
#define BC     16
#define NWG    (BATCH / BC)   // 32
#define DSTEPS 32
#define NG     2048           // 4*H

// packed fragment counts (each fragment = 64 lanes * 16B = 1 KiB)
#define GFRAGS (NLAYER * 128 * 8 * 64)   // gates: [l][ntile=128][ktile=8][lane]
#define PFRAGS (NLAYER * 8 * 16 * 64)    // proj : [l][ntile=8][ktile=16][lane]
#define FFRAGS (8 * 4 * 64)              // fc   : [ntile=8][ktile=4][lane]

static __device__ __forceinline__ unsigned short f2b(float f) {
    union { float f; unsigned int u; } v; v.f = f;
    unsigned int r = v.u + 0x7fffu + ((v.u >> 16) & 1u);  // RNE
    return (unsigned short)(r >> 16);
}
static __device__ __forceinline__ float b2f(unsigned short s) {
    union { float f; unsigned int u; } v; v.u = ((unsigned int)s) << 16;
    return v.f;
}
static __device__ __forceinline__ float sigf(float x) {
    x = fminf(fmaxf(x, -30.f), 30.f);
    return 1.f / (1.f + __expf(-x));
}
static __device__ __forceinline__ float tanh_fast(float x) {
    x = fminf(fmaxf(x, -15.f), 15.f);
    float t = __expf(-2.f * x);
    return (1.f - t) / (1.f + t);
}
static __device__ __forceinline__ f4v mfma16(s8v a, s8v b, f4v c) {
    return __builtin_amdgcn_mfma_f32_16x16x32_bf16(a, b, c, 0, 0, 0);
}

// ---------------------------------------------------------------------------
// Prepack: fp32 weights -> bf16 MFMA B-fragment-linear layout, bias sum,
// and zero the fp32 c-state. One thread per 16B fragment slice / element.
// B-frag layout assumed: lane holds B[k = kt*32 + (lane>>4)*8 + e][n = nt*16 + (lane&15)]
// (matching A: lane holds A[m = lane&15][k = kt*32 + (lane>>4)*8 + e]; any shared
//  within-k permutation cancels between A and B.)
// ---------------------------------------------------------------------------
__global__ __launch_bounds__(256) void lstm_prepack(
    const float* __restrict__ Wih, const float* __restrict__ Whh,
    const float* __restrict__ bih, const float* __restrict__ bhh,
    const float* __restrict__ Whr, const float* __restrict__ Wfc,
    const float* __restrict__ bfcin,
    unsigned short* __restrict__ gB, unsigned short* __restrict__ pB,
    unsigned short* __restrict__ fB, float* __restrict__ bsum,
    float* __restrict__ bfc, float* __restrict__ cst)
{
    int tid = blockIdx.x * 256 + threadIdx.x;

    if (tid < GFRAGS) {  // gates: cat(Wih, Whh) over K=256
        const int lane = tid & 63;
        int rest = tid >> 6;
        const int kt = rest & 7;   rest >>= 3;
        const int nt = rest & 127; rest >>= 7;
        const int l  = rest;
        const int n  = nt * 16 + (lane & 15);
        const int kb = kt * 32 + (lane >> 4) * 8;   // blocks of 32 never straddle k=128
        const float* src = (kb < 128)
            ? (Wih + ((size_t)l * NG + n) * PROJ + kb)
            : (Whh + ((size_t)l * NG + n) * PROJ + (kb - 128));
        unsigned short o[8];
        #pragma unroll
        for (int e = 0; e < 8; ++e) o[e] = f2b(src[e]);
        *(s8v*)(gB + (size_t)tid * 8) = *(const s8v*)o;
        return;
    }
    tid -= GFRAGS;
    if (tid < PFRAGS) {  // proj: Whr (p x 512), B[k][p] = Whr[p][k]
        const int lane = tid & 63;
        int rest = tid >> 6;
        const int kt = rest & 15; rest >>= 4;
        const int nt = rest & 7;  rest >>= 3;
        const int l  = rest;
        const int n  = nt * 16 + (lane & 15);
        const int kb = kt * 32 + (lane >> 4) * 8;
        const float* src = Whr + ((size_t)l * PROJ + n) * HID + kb;
        unsigned short o[8];
        #pragma unroll
        for (int e = 0; e < 8; ++e) o[e] = f2b(src[e]);
        *(s8v*)(pB + (size_t)tid * 8) = *(const s8v*)o;
        return;
    }
    tid -= PFRAGS;
    if (tid < FFRAGS) {  // fc: Wfc (128x128)
        const int lane = tid & 63;
        int rest = tid >> 6;
        const int kt = rest & 3;
        const int nt = rest >> 2;
        const int n  = nt * 16 + (lane & 15);
        const int kb = kt * 32 + (lane >> 4) * 8;
        const float* src = Wfc + (size_t)n * PROJ + kb;
        unsigned short o[8];
        #pragma unroll
        for (int e = 0; e < 8; ++e) o[e] = f2b(src[e]);
        *(s8v*)(fB + (size_t)tid * 8) = *(const s8v*)o;
        return;
    }
    tid -= FFRAGS;
    if (tid < NLAYER * NG) { bsum[tid] = bih[tid] + bhh[tid]; return; }
    tid -= NLAYER * NG;
    if (tid < PROJ) { bfc[tid] = bfcin[tid]; return; }
    tid -= PROJ;
    if (tid < NLAYER * HID * BATCH / 4) {  // zero c-state
        ((float4*)cst)[tid] = make_float4(0.f, 0.f, 0.f, 0.f);
        return;
    }
}

// ---------------------------------------------------------------------------
// Main: 32 workgroups x 512 threads (8 waves). Each wg owns 16 batch rows and
// runs the entire network (encode T=512, decode 32 steps + FC) with no
// inter-workgroup communication. Wave w owns hidden slice j in [w*64, w*64+64)
// of all 4 gates, so i/f/g/o for a (m,j) pair land in the same lane.
// ---------------------------------------------------------------------------
__global__ __launch_bounds__(512) void lstm_main(
    const float* __restrict__ x,               // [512][512][128] fp32
    const unsigned short* __restrict__ gB,
    const unsigned short* __restrict__ pB,
    const unsigned short* __restrict__ fB,
    const float* __restrict__ bsum,            // [6][2048]
    const float* __restrict__ bfc,             // [128]
    float* __restrict__ cst,                   // [6][512(H)][512(B)] fp32
    float* __restrict__ out)                   // [512][32][128] fp32
{
    // padded strides chosen for 16B alignment + low bank conflict
    __shared__ __align__(16) unsigned short xcat[16][280];    // A = [xt | h_rec], K=256
    __shared__ __align__(16) unsigned short hfullA[16][520];  // h_full bf16 for proj A
    __shared__ __align__(16) unsigned short hstate[NLAYER][16][PROJ];

    const int tid  = threadIdx.x;
    const int lane = tid & 63;
    const int w    = tid >> 6;          // wave 0..7
    const int bb   = blockIdx.x * BC;
    const int mrow = lane & 15;
    const int kgrp = lane >> 4;
    const int cm   = tid >> 5;          // copy row   (16 rows)
    const int ck   = (tid & 31) << 2;   // copy col*4 (128 cols)

    for (int i = tid; i < NLAYER * 16 * PROJ; i += 512)
        ((unsigned short*)hstate)[i] = 0;
    __syncthreads();

    const s8v* gfrag = (const s8v*)gB;
    const s8v* pfrag = (const s8v*)pB;
    const s8v* ffrag = (const s8v*)fB;

    #pragma unroll 1
    for (int phase = 0; phase < 2; ++phase) {
      const int tsteps = (phase == 0) ? SEQT : DSTEPS;
      #pragma unroll 1
      for (int t = 0; t < tsteps; ++t) {
        #pragma unroll 1
        for (int l = 0; l < NLAYER; ++l) {
          // ---- build A = [xt (k<128) | h_rec (k>=128)] ----
          if (l == 0) {
            if (phase == 0) {
              const float4 v = *(const float4*)(x + (((size_t)(bb + cm)) * SEQT + t) * PROJ + ck);
              xcat[cm][ck + 0] = f2b(v.x);
              xcat[cm][ck + 1] = f2b(v.y);
              xcat[cm][ck + 2] = f2b(v.z);
              xcat[cm][ck + 3] = f2b(v.w);
            } else {  // decode: zero input
              xcat[cm][ck + 0] = 0; xcat[cm][ck + 1] = 0;
              xcat[cm][ck + 2] = 0; xcat[cm][ck + 3] = 0;
            }
          } else {
            #pragma unroll
            for (int i = 0; i < 4; ++i) xcat[cm][ck + i] = hstate[l - 1][cm][ck + i];
          }
          #pragma unroll
          for (int i = 0; i < 4; ++i) xcat[cm][128 + ck + i] = hstate[l][cm][ck + i];
          __syncthreads();

          // ---- gates GEMM: [16 x 256] @ [256 x 2048], wave owns 4 gates x 64 j ----
          f4v acc[16];
          const int wj0 = w * 64;
          #pragma unroll
          for (int g = 0; g < 4; ++g)
            #pragma unroll
            for (int jt = 0; jt < 4; ++jt) {
              const float b = bsum[l * NG + g * HID + wj0 + jt * 16 + mrow];
              acc[g * 4 + jt] = (f4v){b, b, b, b};
            }
          #pragma unroll
          for (int kt = 0; kt < 8; ++kt) {
            const s8v a = *(const s8v*)&xcat[mrow][kt * 32 + kgrp * 8];
            #pragma unroll
            for (int g = 0; g < 4; ++g)
              #pragma unroll
              for (int jt = 0; jt < 4; ++jt) {
                const int nt = g * 32 + w * 4 + jt;
                const s8v bf = gfrag[(((size_t)l * 128 + nt) * 8 + kt) * 64 + lane];
                acc[g * 4 + jt] = mfma16(a, bf, acc[g * 4 + jt]);
              }
          }

          // ---- pointwise: c update (fp32, global), h_full -> LDS bf16 ----
          #pragma unroll
          for (int jt = 0; jt < 4; ++jt) {
            const int j = wj0 + jt * 16 + mrow;
            float* cp = cst + (((size_t)l * HID + j) * BATCH + bb + kgrp * 4);
            float4 c4 = *(float4*)cp;
            float cc[4] = {c4.x, c4.y, c4.z, c4.w};
            #pragma unroll
            for (int r = 0; r < 4; ++r) {
              const float iv = acc[0  + jt][r];
              const float fv = acc[4  + jt][r];
              const float gv = acc[8  + jt][r];
              const float ov = acc[12 + jt][r];
              const float ci = sigf(fv) * cc[r] + sigf(iv) * tanh_fast(gv);
              const float hf = sigf(ov) * tanh_fast(ci);
              cc[r] = ci;
              hfullA[kgrp * 4 + r][j] = f2b(hf);
            }
            *(float4*)cp = make_float4(cc[0], cc[1], cc[2], cc[3]);
          }
          __syncthreads();

          // ---- proj GEMM: [16 x 512] @ [512 x 128], wave w -> p tile w ----
          f4v pacc = (f4v){0.f, 0.f, 0.f, 0.f};
          #pragma unroll
          for (int kt = 0; kt < 16; ++kt) {
            const s8v a  = *(const s8v*)&hfullA[mrow][kt * 32 + kgrp * 8];
            const s8v bf = pfrag[(((size_t)l * 8 + w) * 16 + kt) * 64 + lane];
            pacc = mfma16(a, bf, pacc);
          }
          #pragma unroll
          for (int r = 0; r < 4; ++r)
            hstate[l][kgrp * 4 + r][w * 16 + mrow] = f2b(pacc[r]);
          __syncthreads();
        } // l

        if (phase == 1) {
          // ---- FC head: out = sigmoid(h5) @ Wfc^T + bfc ----
          #pragma unroll
          for (int i = 0; i < 4; ++i)
            xcat[cm][ck + i] = f2b(sigf(b2f(hstate[NLAYER - 1][cm][ck + i])));
          __syncthreads();
          const int p = w * 16 + mrow;
          const float bv = bfc[p];
          f4v facc = (f4v){bv, bv, bv, bv};
          #pragma unroll
          for (int kt = 0; kt < 4; ++kt) {
            const s8v a  = *(const s8v*)&xcat[mrow][kt * 32 + kgrp * 8];
            const s8v bf = ffrag[((size_t)w * 4 + kt) * 64 + lane];
            facc = mfma16(a, bf, facc);
          }
          #pragma unroll
          for (int r = 0; r < 4; ++r)
            out[(((size_t)(bb + kgrp * 4 + r)) * DSTEPS + t) * PROJ + p] = facc[r];
          __syncthreads();
        }
      } // t
    } // phase
}

extern "C" void kernel_launch(void* const* d_in, const int* in_sizes, int n_in,
                              void* d_out, int out_size, void* d_ws, size_t ws_size,
                              hipStream_t stream)
{
    const float* x    = (const float*)d_in[0];
    const float* Wih  = (const float*)d_in[1];
    const float* Whh  = (const float*)d_in[2];
    const float* bih  = (const float*)d_in[3];
    const float* bhh  = (const float*)d_in[4];
    const float* Whr  = (const float*)d_in[5];
    const float* Wfc  = (const float*)d_in[6];
    const float* bfcv = (const float*)d_in[7];

    char* ws = (char*)d_ws;
    size_t off = 0;
    auto alloc = [&](size_t b) { char* p = ws + off; off += (b + 255) & ~(size_t)255; return p; };
    unsigned short* gB = (unsigned short*)alloc((size_t)GFRAGS * 16);
    unsigned short* pB = (unsigned short*)alloc((size_t)PFRAGS * 16);
    unsigned short* fB = (unsigned short*)alloc((size_t)FFRAGS * 16);
    float* bsum = (float*)alloc((size_t)NLAYER * NG * 4);
    float* bfc  = (float*)alloc((size_t)PROJ * 4);
    float* cst  = (float*)alloc((size_t)NLAYER * HID * BATCH * 4);
    if (off > ws_size) return;  // workspace too small; fail validation cleanly

    const int total = GFRAGS + PFRAGS + FFRAGS + NLAYER * NG + PROJ + NLAYER * HID * BATCH / 4;
    lstm_prepack<<<(total + 255) / 256, 256, 0, stream>>>(
        Wih, Whh, bih, bhh, Whr, Wfc, bfcv, gB, pB, fB, bsum, bfc, cst);
    lstm_main<<<NWG, 512, 0, stream>>>(x, gB, pB, fB, bsum, bfc, cst, (float*)d_out);
}

// Round 2
// 32944.760 us; speedup vs baseline: 3.4215x; 3.4215x over previous
//
#include <hip/hip_runtime.h>

typedef short s8v __attribute__((ext_vector_type(8)));
typedef unsigned short u8v __attribute__((ext_vector_type(8)));
typedef float f4v __attribute__((ext_vector_type(4)));
typedef unsigned long long ull;

#define NLAYER 6
#define HID    512
#define PROJ   128
#define SEQT   512
#define BATCH  512
#define DSTEPS 32
#define TOTS   (SEQT + DSTEPS)   // 544
#define NG     2048              // 4*H
#define BC     32                // batch rows per WG
#define NCHUNK (BATCH / BC)      // 16
#define RINGD  32                // ring depth (steps)

// packed fragment counts (each fragment = 64 lanes * 16B = 1 KiB)
#define GFRAGS (NLAYER * 128 * 8 * 64)   // gates: [l][ntile=128][ktile=8][lane]
#define PFRAGS (NLAYER * 8 * 16 * 64)    // proj : [l][ntile=8][ktile=16][lane]
#define FFRAGS (8 * 4 * 64)              // fc   : [ntile=8][ktile=4][lane]
#define NFLAGS (2 * 5 * NCHUNK)          // hflag[5][16] then aflag[5][16]
#define SLOT_ULL 1024                    // 32*128 bf16 = 8 KB = 1024 ull
#define RING_ULL ((size_t)5 * NCHUNK * RINGD * SLOT_ULL)

static __device__ __forceinline__ unsigned short f2b(float f) {
    union { float f; unsigned int u; } v; v.f = f;
    unsigned int r = v.u + 0x7fffu + ((v.u >> 16) & 1u);  // RNE
    return (unsigned short)(r >> 16);
}
static __device__ __forceinline__ float b2f(unsigned short s) {
    union { float f; unsigned int u; } v; v.u = ((unsigned int)s) << 16;
    return v.f;
}
static __device__ __forceinline__ float sigf(float x) {
    x = fminf(fmaxf(x, -30.f), 30.f);
    return 1.f / (1.f + __expf(-x));
}
static __device__ __forceinline__ float tanh_fast(float x) {
    x = fminf(fmaxf(x, -15.f), 15.f);
    float t = __expf(-2.f * x);
    return (1.f - t) / (1.f + t);
}
static __device__ __forceinline__ f4v mfma16(s8v a, s8v b, f4v c) {
    return __builtin_amdgcn_mfma_f32_16x16x32_bf16(a, b, c, 0, 0, 0);
}

// ---------------------------------------------------------------------------
// Prepack: fp32 weights -> bf16 MFMA B-fragment-linear layout, bias sum,
// zero sync flags. (identical fragment layout to the round-1 kernel, which
// passed validation)
// ---------------------------------------------------------------------------
__global__ __launch_bounds__(256) void lstm_prepack(
    const float* __restrict__ Wih, const float* __restrict__ Whh,
    const float* __restrict__ bih, const float* __restrict__ bhh,
    const float* __restrict__ Whr, const float* __restrict__ Wfc,
    const float* __restrict__ bfcin,
    unsigned short* __restrict__ gB, unsigned short* __restrict__ pB,
    unsigned short* __restrict__ fB, float* __restrict__ bsum,
    float* __restrict__ bfc, unsigned int* __restrict__ flags)
{
    int tid = blockIdx.x * 256 + threadIdx.x;

    if (tid < GFRAGS) {  // gates: cat(Wih, Whh) over K=256
        const int lane = tid & 63;
        int rest = tid >> 6;
        const int kt = rest & 7;   rest >>= 3;
        const int nt = rest & 127; rest >>= 7;
        const int l  = rest;
        const int n  = nt * 16 + (lane & 15);
        const int kb = kt * 32 + (lane >> 4) * 8;
        const float* src = (kb < 128)
            ? (Wih + ((size_t)l * NG + n) * PROJ + kb)
            : (Whh + ((size_t)l * NG + n) * PROJ + (kb - 128));
        unsigned short o[8];
        #pragma unroll
        for (int e = 0; e < 8; ++e) o[e] = f2b(src[e]);
        *(s8v*)(gB + (size_t)tid * 8) = *(const s8v*)o;
        return;
    }
    tid -= GFRAGS;
    if (tid < PFRAGS) {  // proj: Whr (p x 512), B[k][p] = Whr[p][k]
        const int lane = tid & 63;
        int rest = tid >> 6;
        const int kt = rest & 15; rest >>= 4;
        const int nt = rest & 7;  rest >>= 3;
        const int l  = rest;
        const int n  = nt * 16 + (lane & 15);
        const int kb = kt * 32 + (lane >> 4) * 8;
        const float* src = Whr + ((size_t)l * PROJ + n) * HID + kb;
        unsigned short o[8];
        #pragma unroll
        for (int e = 0; e < 8; ++e) o[e] = f2b(src[e]);
        *(s8v*)(pB + (size_t)tid * 8) = *(const s8v*)o;
        return;
    }
    tid -= PFRAGS;
    if (tid < FFRAGS) {  // fc: Wfc (128x128)
        const int lane = tid & 63;
        int rest = tid >> 6;
        const int kt = rest & 3;
        const int nt = rest >> 2;
        const int n  = nt * 16 + (lane & 15);
        const int kb = kt * 32 + (lane >> 4) * 8;
        const float* src = Wfc + (size_t)n * PROJ + kb;
        unsigned short o[8];
        #pragma unroll
        for (int e = 0; e < 8; ++e) o[e] = f2b(src[e]);
        *(s8v*)(fB + (size_t)tid * 8) = *(const s8v*)o;
        return;
    }
    tid -= FFRAGS;
    if (tid < NLAYER * NG) { bsum[tid] = bih[tid] + bhh[tid]; return; }
    tid -= NLAYER * NG;
    if (tid < PROJ) { bfc[tid] = bfcin[tid]; return; }
    tid -= PROJ;
    if (tid < NFLAGS) { flags[tid] = 0u; return; }
}

// ---------------------------------------------------------------------------
// Main: 128 blocks x 512 threads. blockIdx = chunk*8 + l (l>=6 exits), so
// layer l's 16 WGs land on XCD l (round-robin dispatch) and its 1.28 MiB of
// weights stay resident in that XCD's L2. Each WG owns 32 batch rows of one
// layer; layers pipeline via ring buffers + flags (relaxed agent atomics for
// data — no cache-invalidating acquire fences — release only on the flag).
// c-state lives in registers; h recurrent state lives in LDS.
// ---------------------------------------------------------------------------
__global__ __launch_bounds__(512, 2) void lstm_main(
    const float* __restrict__ x,               // [512][512][128] fp32
    const unsigned short* __restrict__ gB,
    const unsigned short* __restrict__ pB,
    const unsigned short* __restrict__ fB,
    const float* __restrict__ bsum,            // [6][2048]
    const float* __restrict__ bfc,             // [128]
    unsigned int* __restrict__ flags,          // [hflag 5*16][aflag 5*16]
    ull* __restrict__ ring,                    // [5][16][RINGD][1024]
    float* __restrict__ out)                   // [512][32][128] fp32
{
    const int l = blockIdx.x & 7;
    if (l >= NLAYER) return;
    const int chunk = blockIdx.x >> 3;
    const int bb = chunk * BC;

    __shared__ __align__(16) unsigned short xcat[32][264];    // A=[xt | h_rec], K=256
    __shared__ __align__(16) unsigned short hfullA[32][520];  // h_full bf16 (proj A)

    const int tid  = threadIdx.x;
    const int lane = tid & 63;
    const int w    = tid >> 6;          // wave 0..7
    const int mrow = lane & 15;
    const int kgrp = lane >> 4;
    const int cr   = tid >> 4;          // copy row 0..31
    const int cq   = (tid & 15) * 8;    // copy col (shorts), step 8

    for (int i = tid; i < 32 * 264; i += 512) ((unsigned short*)xcat)[i] = 0;

    const s8v* gW = (const s8v*)gB + (size_t)l * 128 * 8 * 64;
    const s8v* pW = (const s8v*)pB + (size_t)l * 8 * 16 * 64;
    const s8v* fW = (const s8v*)fB;
    unsigned int* hfl = flags;                 // [5][16]
    unsigned int* afl = flags + 5 * NCHUNK;    // [5][16]

    // bias preload: wave w owns j in [w*64, w*64+64) of each gate
    float bias[16];
    #pragma unroll
    for (int g = 0; g < 4; ++g)
      #pragma unroll
      for (int jt = 0; jt < 4; ++jt)
        bias[g * 4 + jt] = bsum[l * NG + g * HID + w * 64 + jt * 16 + mrow];

    // c-state in registers: j = w*64+jt*16+mrow, m = mt*16+kgrp*4+r
    f4v cst[4][2];
    #pragma unroll
    for (int jt = 0; jt < 4; ++jt)
      #pragma unroll
      for (int mt = 0; mt < 2; ++mt)
        cst[jt][mt] = (f4v){0.f, 0.f, 0.f, 0.f};

    __syncthreads();

    #pragma unroll 1
    for (int s = 0; s < TOTS; ++s) {
        // ---- A: polls (upstream data ready; downstream ring slot free) ----
        if (tid == 0) {
            if (l > 0) {
                while (__hip_atomic_load(&hfl[(l - 1) * NCHUNK + chunk],
                        __ATOMIC_RELAXED, __HIP_MEMORY_SCOPE_AGENT) < (unsigned)(s + 1))
                    __builtin_amdgcn_s_sleep(2);
            }
            if (l < NLAYER - 1 && s >= RINGD) {
                while (__hip_atomic_load(&afl[l * NCHUNK + chunk],
                        __ATOMIC_RELAXED, __HIP_MEMORY_SCOPE_AGENT) < (unsigned)(s - RINGD + 1))
                    __builtin_amdgcn_s_sleep(2);
            }
        }
        __syncthreads();

        // ---- input build (xcat lower half) ----
        if (l == 0) {
            if (s < SEQT) {
                const float* xp = x + (((size_t)(bb + cr)) * SEQT + s) * PROJ + cq;
                const float4 v0 = *(const float4*)xp;
                const float4 v1 = *(const float4*)(xp + 4);
                u8v o;
                o[0] = f2b(v0.x); o[1] = f2b(v0.y); o[2] = f2b(v0.z); o[3] = f2b(v0.w);
                o[4] = f2b(v1.x); o[5] = f2b(v1.y); o[6] = f2b(v1.z); o[7] = f2b(v1.w);
                *(u8v*)&xcat[cr][cq] = o;
            } else {
                *(ull*)&xcat[cr][cq]     = 0ull;
                *(ull*)&xcat[cr][cq + 4] = 0ull;
            }
        } else {
            const ull* rb = ring + (((size_t)(l - 1) * NCHUNK + chunk) * RINGD
                                    + (s & (RINGD - 1))) * SLOT_ULL
                                 + cr * 32 + (tid & 15) * 2;
            const ull v0 = __hip_atomic_load(rb,     __ATOMIC_RELAXED, __HIP_MEMORY_SCOPE_AGENT);
            const ull v1 = __hip_atomic_load(rb + 1, __ATOMIC_RELAXED, __HIP_MEMORY_SCOPE_AGENT);
            *(ull*)&xcat[cr][cq]     = v0;
            *(ull*)&xcat[cr][cq + 4] = v1;
        }
        __syncthreads();   // xcat ready (drains each wave's loads -> safe to ack)
        if (tid == 0 && l > 0)
            __hip_atomic_store(&afl[(l - 1) * NCHUNK + chunk], (unsigned)(s + 1),
                               __ATOMIC_RELAXED, __HIP_MEMORY_SCOPE_AGENT);

        // ---- gates GEMM: [32 x 256] @ [256 x 2048] ----
        f4v acc[4][4][2];
        #pragma unroll
        for (int g = 0; g < 4; ++g)
          #pragma unroll
          for (int jt = 0; jt < 4; ++jt) {
            const float b = bias[g * 4 + jt];
            acc[g][jt][0] = (f4v){b, b, b, b};
            acc[g][jt][1] = (f4v){b, b, b, b};
          }
        #pragma unroll
        for (int kt = 0; kt < 8; ++kt) {
            const s8v a0 = *(const s8v*)&xcat[mrow][kt * 32 + kgrp * 8];
            const s8v a1 = *(const s8v*)&xcat[16 + mrow][kt * 32 + kgrp * 8];
            #pragma unroll
            for (int g = 0; g < 4; ++g)
              #pragma unroll
              for (int jt = 0; jt < 4; ++jt) {
                const s8v bf = gW[(((size_t)(g * 32 + w * 4 + jt)) * 8 + kt) * 64 + lane];
                acc[g][jt][0] = mfma16(a0, bf, acc[g][jt][0]);
                acc[g][jt][1] = mfma16(a1, bf, acc[g][jt][1]);
              }
        }

        // ---- pointwise: c in regs, h_full -> LDS bf16 ----
        #pragma unroll
        for (int jt = 0; jt < 4; ++jt)
          #pragma unroll
          for (int mt = 0; mt < 2; ++mt) {
            f4v cv = cst[jt][mt];
            #pragma unroll
            for (int r = 0; r < 4; ++r) {
                const float iv = acc[0][jt][mt][r];
                const float fv = acc[1][jt][mt][r];
                const float gv = acc[2][jt][mt][r];
                const float ov = acc[3][jt][mt][r];
                const float cn = sigf(fv) * cv[r] + sigf(iv) * tanh_fast(gv);
                const float hf = sigf(ov) * tanh_fast(cn);
                cv[r] = cn;
                hfullA[mt * 16 + kgrp * 4 + r][w * 64 + jt * 16 + mrow] = f2b(hf);
            }
            cst[jt][mt] = cv;
          }
        __syncthreads();   // hfullA ready; xcat reads done

        // ---- proj GEMM: [32 x 512] @ [512 x 128], wave w -> p tile w ----
        f4v p0 = (f4v){0.f, 0.f, 0.f, 0.f};
        f4v p1 = (f4v){0.f, 0.f, 0.f, 0.f};
        #pragma unroll
        for (int kt = 0; kt < 16; ++kt) {
            const s8v a0 = *(const s8v*)&hfullA[mrow][kt * 32 + kgrp * 8];
            const s8v a1 = *(const s8v*)&hfullA[16 + mrow][kt * 32 + kgrp * 8];
            const s8v bf = pW[((size_t)w * 16 + kt) * 64 + lane];
            p0 = mfma16(a0, bf, p0);
            p1 = mfma16(a1, bf, p1);
        }
        // write h(s) into xcat upper (next step's recurrent input)
        #pragma unroll
        for (int r = 0; r < 4; ++r) {
            xcat[kgrp * 4 + r][128 + w * 16 + mrow]      = f2b(p0[r]);
            xcat[16 + kgrp * 4 + r][128 + w * 16 + mrow] = f2b(p1[r]);
        }
        __syncthreads();   // xcat upper ready

        // ---- publish h(s) to downstream ring ----
        if (l < NLAYER - 1) {
            const ull v0 = *(const ull*)&xcat[cr][128 + cq];
            const ull v1 = *(const ull*)&xcat[cr][128 + cq + 4];
            ull* rb = ring + (((size_t)l * NCHUNK + chunk) * RINGD
                              + (s & (RINGD - 1))) * SLOT_ULL
                           + cr * 32 + (tid & 15) * 2;
            __hip_atomic_store(rb,     v0, __ATOMIC_RELAXED, __HIP_MEMORY_SCOPE_AGENT);
            __hip_atomic_store(rb + 1, v1, __ATOMIC_RELAXED, __HIP_MEMORY_SCOPE_AGENT);
            __syncthreads();   // drains all waves' ring stores (vmcnt at barrier)
            if (tid == 0)
                __hip_atomic_store(&hfl[l * NCHUNK + chunk], (unsigned)(s + 1),
                                   __ATOMIC_RELEASE, __HIP_MEMORY_SCOPE_AGENT);
        }

        // ---- FC head (decode, last layer): out = sigmoid(h5) @ Wfc^T + bfc ----
        if (l == NLAYER - 1 && s >= SEQT) {
            for (int i = tid; i < 32 * PROJ; i += 512) {
                const int r = i >> 7, c = i & 127;
                hfullA[r][c] = f2b(sigf(b2f(xcat[r][128 + c])));
            }
            __syncthreads();
            const float bv = bfc[w * 16 + mrow];
            f4v f0 = (f4v){bv, bv, bv, bv};
            f4v f1 = (f4v){bv, bv, bv, bv};
            #pragma unroll
            for (int kt = 0; kt < 4; ++kt) {
                const s8v a0 = *(const s8v*)&hfullA[mrow][kt * 32 + kgrp * 8];
                const s8v a1 = *(const s8v*)&hfullA[16 + mrow][kt * 32 + kgrp * 8];
                const s8v bf = fW[((size_t)w * 4 + kt) * 64 + lane];
                f0 = mfma16(a0, bf, f0);
                f1 = mfma16(a1, bf, f1);
            }
            const int td = s - SEQT;
            #pragma unroll
            for (int r = 0; r < 4; ++r) {
                out[(((size_t)(bb + kgrp * 4 + r)) * DSTEPS + td) * PROJ + w * 16 + mrow]      = f0[r];
                out[(((size_t)(bb + 16 + kgrp * 4 + r)) * DSTEPS + td) * PROJ + w * 16 + mrow] = f1[r];
            }
            __syncthreads();   // hfullA reuse guard before next step's pointwise
        }
    }
}

extern "C" void kernel_launch(void* const* d_in, const int* in_sizes, int n_in,
                              void* d_out, int out_size, void* d_ws, size_t ws_size,
                              hipStream_t stream)
{
    const float* x    = (const float*)d_in[0];
    const float* Wih  = (const float*)d_in[1];
    const float* Whh  = (const float*)d_in[2];
    const float* bih  = (const float*)d_in[3];
    const float* bhh  = (const float*)d_in[4];
    const float* Whr  = (const float*)d_in[5];
    const float* Wfc  = (const float*)d_in[6];
    const float* bfcv = (const float*)d_in[7];

    char* ws = (char*)d_ws;
    size_t off = 0;
    auto alloc = [&](size_t b) { char* p = ws + off; off += (b + 255) & ~(size_t)255; return p; };
    unsigned short* gB  = (unsigned short*)alloc((size_t)GFRAGS * 16);
    unsigned short* pB  = (unsigned short*)alloc((size_t)PFRAGS * 16);
    unsigned short* fB  = (unsigned short*)alloc((size_t)FFRAGS * 16);
    float* bsum         = (float*)alloc((size_t)NLAYER * NG * 4);
    float* bfc          = (float*)alloc((size_t)PROJ * 4);
    unsigned int* flags = (unsigned int*)alloc((size_t)NFLAGS * 4);
    ull* ring           = (ull*)alloc(RING_ULL * 8);
    if (off > ws_size) return;  // workspace too small; fail validation cleanly

    const int total = GFRAGS + PFRAGS + FFRAGS + NLAYER * NG + PROJ + NFLAGS;
    lstm_prepack<<<(total + 255) / 256, 256, 0, stream>>>(
        Wih, Whh, bih, bhh, Whr, Wfc, bfcv, gB, pB, fB, bsum, bfc, flags);
    lstm_main<<<NCHUNK * 8, 512, 0, stream>>>(
        x, gB, pB, fB, bsum, bfc, flags, ring, (float*)d_out);
}

// Round 3
// 31969.037 us; speedup vs baseline: 3.5259x; 1.0305x over previous
//
#include <hip/hip_runtime.h>

typedef short s8v __attribute__((ext_vector_type(8)));
typedef unsigned short u8v __attribute__((ext_vector_type(8)));
typedef float f4v __attribute__((ext_vector_type(4)));
typedef unsigned long long ull;

#define NLAYER 6
#define HID    512
#define PROJ   128
#define SEQT   512
#define BATCH  512
#define DSTEPS 32
#define TOTS   (SEQT + DSTEPS)   // 544
#define NG     2048              // 4*H
#define BC     32                // batch rows per WG
#define NCHUNK (BATCH / BC)      // 16
#define RINGD  32                // ring depth (steps)

// packed fragment counts (each fragment = 64 lanes * 16B = 1 KiB)
#define GFRAGS (NLAYER * 128 * 8 * 64)   // gates: [l][ntile=128][ktile=8][lane]
#define PFRAGS (NLAYER * 8 * 16 * 64)    // proj : [l][ntile=8][ktile=16][lane]
#define FFRAGS (8 * 4 * 64)              // fc   : [ntile=8][ktile=4][lane]
#define NFLAGS (2 * 5 * NCHUNK)          // hflag[5][16] then aflag[5][16]
#define SLOT_ULL 1024                    // 32*128 bf16 = 8 KB = 1024 ull
#define RING_ULL ((size_t)5 * NCHUNK * RINGD * SLOT_ULL)

static __device__ __forceinline__ unsigned short f2b(float f) {
    union { float f; unsigned int u; } v; v.f = f;
    unsigned int r = v.u + 0x7fffu + ((v.u >> 16) & 1u);  // RNE
    return (unsigned short)(r >> 16);
}
static __device__ __forceinline__ float b2f(unsigned short s) {
    union { float f; unsigned int u; } v; v.u = ((unsigned int)s) << 16;
    return v.f;
}
static __device__ __forceinline__ float sigf(float x) {
    x = fminf(fmaxf(x, -30.f), 30.f);
    return 1.f / (1.f + __expf(-x));
}
static __device__ __forceinline__ float tanh_fast(float x) {
    x = fminf(fmaxf(x, -15.f), 15.f);
    float t = __expf(-2.f * x);
    return (1.f - t) / (1.f + t);
}
static __device__ __forceinline__ f4v mfma16(s8v a, s8v b, f4v c) {
    return __builtin_amdgcn_mfma_f32_16x16x32_bf16(a, b, c, 0, 0, 0);
}

// ---------------------------------------------------------------------------
// Prepack: fp32 weights -> bf16 MFMA B-fragment-linear layout, bias sum,
// zero sync flags. (identical fragment layout to rounds 1-2, which passed)
// ---------------------------------------------------------------------------
__global__ __launch_bounds__(256) void lstm_prepack(
    const float* __restrict__ Wih, const float* __restrict__ Whh,
    const float* __restrict__ bih, const float* __restrict__ bhh,
    const float* __restrict__ Whr, const float* __restrict__ Wfc,
    const float* __restrict__ bfcin,
    unsigned short* __restrict__ gB, unsigned short* __restrict__ pB,
    unsigned short* __restrict__ fB, float* __restrict__ bsum,
    float* __restrict__ bfc, unsigned int* __restrict__ flags)
{
    int tid = blockIdx.x * 256 + threadIdx.x;

    if (tid < GFRAGS) {  // gates: cat(Wih, Whh) over K=256
        const int lane = tid & 63;
        int rest = tid >> 6;
        const int kt = rest & 7;   rest >>= 3;
        const int nt = rest & 127; rest >>= 7;
        const int l  = rest;
        const int n  = nt * 16 + (lane & 15);
        const int kb = kt * 32 + (lane >> 4) * 8;
        const float* src = (kb < 128)
            ? (Wih + ((size_t)l * NG + n) * PROJ + kb)
            : (Whh + ((size_t)l * NG + n) * PROJ + (kb - 128));
        unsigned short o[8];
        #pragma unroll
        for (int e = 0; e < 8; ++e) o[e] = f2b(src[e]);
        *(s8v*)(gB + (size_t)tid * 8) = *(const s8v*)o;
        return;
    }
    tid -= GFRAGS;
    if (tid < PFRAGS) {  // proj: Whr (p x 512), B[k][p] = Whr[p][k]
        const int lane = tid & 63;
        int rest = tid >> 6;
        const int kt = rest & 15; rest >>= 4;
        const int nt = rest & 7;  rest >>= 3;
        const int l  = rest;
        const int n  = nt * 16 + (lane & 15);
        const int kb = kt * 32 + (lane >> 4) * 8;
        const float* src = Whr + ((size_t)l * PROJ + n) * HID + kb;
        unsigned short o[8];
        #pragma unroll
        for (int e = 0; e < 8; ++e) o[e] = f2b(src[e]);
        *(s8v*)(pB + (size_t)tid * 8) = *(const s8v*)o;
        return;
    }
    tid -= PFRAGS;
    if (tid < FFRAGS) {  // fc: Wfc (128x128)
        const int lane = tid & 63;
        int rest = tid >> 6;
        const int kt = rest & 3;
        const int nt = rest >> 2;
        const int n  = nt * 16 + (lane & 15);
        const int kb = kt * 32 + (lane >> 4) * 8;
        const float* src = Wfc + (size_t)n * PROJ + kb;
        unsigned short o[8];
        #pragma unroll
        for (int e = 0; e < 8; ++e) o[e] = f2b(src[e]);
        *(s8v*)(fB + (size_t)tid * 8) = *(const s8v*)o;
        return;
    }
    tid -= FFRAGS;
    if (tid < NLAYER * NG) { bsum[tid] = bih[tid] + bhh[tid]; return; }
    tid -= NLAYER * NG;
    if (tid < PROJ) { bfc[tid] = bfcin[tid]; return; }
    tid -= PROJ;
    if (tid < NFLAGS) { flags[tid] = 0u; return; }
}

// ---------------------------------------------------------------------------
// Main: 96 blocks x 512 threads, one (layer, batch-chunk) per block.
// XCD-locality map (XCD = blockIdx%8 round-robin): g = (b%8)*12 + b/8,
// l = g/16, chunk = g%16  ->  each XCD hosts exactly 12 WGs spanning <=2
// layers (<=2.3 MiB weights, L2-resident). Layers pipeline via ring buffers
// + flags (relaxed agent atomics for data; release only on the flag).
// c-state in registers; bias in LDS; no launch_bounds reg cap (needs ~240).
// ---------------------------------------------------------------------------
__global__ __launch_bounds__(512) void lstm_main(
    const float* __restrict__ x,               // [512][512][128] fp32
    const unsigned short* __restrict__ gB,
    const unsigned short* __restrict__ pB,
    const unsigned short* __restrict__ fB,
    const float* __restrict__ bsum,            // [6][2048]
    const float* __restrict__ bfc,             // [128]
    unsigned int* __restrict__ flags,          // [hflag 5*16][aflag 5*16]
    ull* __restrict__ ring,                    // [5][16][RINGD][1024]
    float* __restrict__ out)                   // [512][32][128] fp32
{
    const int g0    = (blockIdx.x & 7) * 12 + (blockIdx.x >> 3);
    const int l     = g0 >> 4;
    const int chunk = g0 & 15;
    const int bb    = chunk * BC;

    __shared__ __align__(16) unsigned short xcat[32][264];    // A=[xt | h_rec], K=256
    __shared__ __align__(16) unsigned short hfullA[32][520];  // h_full bf16 (proj A)
    __shared__ float biasS[NG];

    const int tid  = threadIdx.x;
    const int lane = tid & 63;
    const int w    = tid >> 6;          // wave 0..7
    const int mrow = lane & 15;
    const int kgrp = lane >> 4;
    const int cr   = tid >> 4;          // copy row 0..31
    const int cq   = (tid & 15) * 8;    // copy col (shorts), step 8

    for (int i = tid; i < 32 * 264; i += 512) ((unsigned short*)xcat)[i] = 0;
    for (int i = tid; i < NG; i += 512) biasS[i] = bsum[l * NG + i];

    const s8v* gW = (const s8v*)gB + (size_t)l * 128 * 8 * 64;
    const s8v* pW = (const s8v*)pB + (size_t)l * 8 * 16 * 64;
    const s8v* fW = (const s8v*)fB;
    unsigned int* hfl = flags;                 // [5][16]
    unsigned int* afl = flags + 5 * NCHUNK;    // [5][16]

    // c-state in registers: j = w*64+jt*16+mrow, m = mt*16+kgrp*4+r
    f4v cst[4][2];
    #pragma unroll
    for (int jt = 0; jt < 4; ++jt)
      #pragma unroll
      for (int mt = 0; mt < 2; ++mt)
        cst[jt][mt] = (f4v){0.f, 0.f, 0.f, 0.f};

    __syncthreads();

    #pragma unroll 1
    for (int s = 0; s < TOTS; ++s) {
        // ---- polls (upstream data ready; downstream ring slot free) ----
        if (tid == 0) {
            if (l > 0) {
                while (__hip_atomic_load(&hfl[(l - 1) * NCHUNK + chunk],
                        __ATOMIC_RELAXED, __HIP_MEMORY_SCOPE_AGENT) < (unsigned)(s + 1))
                    __builtin_amdgcn_s_sleep(2);
            }
            if (l < NLAYER - 1 && s >= RINGD) {
                while (__hip_atomic_load(&afl[l * NCHUNK + chunk],
                        __ATOMIC_RELAXED, __HIP_MEMORY_SCOPE_AGENT) < (unsigned)(s - RINGD + 1))
                    __builtin_amdgcn_s_sleep(2);
            }
        }
        __syncthreads();

        // ---- input build (xcat lower half) ----
        if (l == 0) {
            if (s < SEQT) {
                const float* xp = x + (((size_t)(bb + cr)) * SEQT + s) * PROJ + cq;
                const float4 v0 = *(const float4*)xp;
                const float4 v1 = *(const float4*)(xp + 4);
                u8v o;
                o[0] = f2b(v0.x); o[1] = f2b(v0.y); o[2] = f2b(v0.z); o[3] = f2b(v0.w);
                o[4] = f2b(v1.x); o[5] = f2b(v1.y); o[6] = f2b(v1.z); o[7] = f2b(v1.w);
                *(u8v*)&xcat[cr][cq] = o;
            } else {
                *(ull*)&xcat[cr][cq]     = 0ull;
                *(ull*)&xcat[cr][cq + 4] = 0ull;
            }
        } else {
            const ull* rb = ring + (((size_t)(l - 1) * NCHUNK + chunk) * RINGD
                                    + (s & (RINGD - 1))) * SLOT_ULL
                                 + cr * 32 + (tid & 15) * 2;
            const ull v0 = __hip_atomic_load(rb,     __ATOMIC_RELAXED, __HIP_MEMORY_SCOPE_AGENT);
            const ull v1 = __hip_atomic_load(rb + 1, __ATOMIC_RELAXED, __HIP_MEMORY_SCOPE_AGENT);
            *(ull*)&xcat[cr][cq]     = v0;
            *(ull*)&xcat[cr][cq + 4] = v1;
        }
        __syncthreads();   // xcat ready (drains each wave's loads -> safe to ack)
        if (tid == 0 && l > 0)
            __hip_atomic_store(&afl[(l - 1) * NCHUNK + chunk], (unsigned)(s + 1),
                               __ATOMIC_RELAXED, __HIP_MEMORY_SCOPE_AGENT);

        // ---- gates GEMM: [32 x 256] @ [256 x 2048] ----
        f4v acc[4][4][2];
        #pragma unroll
        for (int gg = 0; gg < 4; ++gg)
          #pragma unroll
          for (int jt = 0; jt < 4; ++jt) {
            const float b = biasS[gg * HID + w * 64 + jt * 16 + mrow];
            acc[gg][jt][0] = (f4v){b, b, b, b};
            acc[gg][jt][1] = (f4v){b, b, b, b};
          }
        #pragma unroll
        for (int kt = 0; kt < 8; ++kt) {
            const s8v a0 = *(const s8v*)&xcat[mrow][kt * 32 + kgrp * 8];
            const s8v a1 = *(const s8v*)&xcat[16 + mrow][kt * 32 + kgrp * 8];
            #pragma unroll
            for (int gg = 0; gg < 4; ++gg)
              #pragma unroll
              for (int jt = 0; jt < 4; ++jt) {
                const s8v bf = gW[(((size_t)(gg * 32 + w * 4 + jt)) * 8 + kt) * 64 + lane];
                acc[gg][jt][0] = mfma16(a0, bf, acc[gg][jt][0]);
                acc[gg][jt][1] = mfma16(a1, bf, acc[gg][jt][1]);
              }
        }

        // ---- pointwise: c in regs, h_full -> LDS bf16 ----
        #pragma unroll
        for (int jt = 0; jt < 4; ++jt)
          #pragma unroll
          for (int mt = 0; mt < 2; ++mt) {
            f4v cv = cst[jt][mt];
            #pragma unroll
            for (int r = 0; r < 4; ++r) {
                const float iv = acc[0][jt][mt][r];
                const float fv = acc[1][jt][mt][r];
                const float gv = acc[2][jt][mt][r];
                const float ov = acc[3][jt][mt][r];
                const float cn = sigf(fv) * cv[r] + sigf(iv) * tanh_fast(gv);
                const float hf = sigf(ov) * tanh_fast(cn);
                cv[r] = cn;
                hfullA[mt * 16 + kgrp * 4 + r][w * 64 + jt * 16 + mrow] = f2b(hf);
            }
            cst[jt][mt] = cv;
          }
        __syncthreads();   // hfullA ready; xcat reads done

        // ---- proj GEMM: [32 x 512] @ [512 x 128], wave w -> p tile w ----
        f4v p0 = (f4v){0.f, 0.f, 0.f, 0.f};
        f4v p1 = (f4v){0.f, 0.f, 0.f, 0.f};
        #pragma unroll
        for (int kt = 0; kt < 16; ++kt) {
            const s8v a0 = *(const s8v*)&hfullA[mrow][kt * 32 + kgrp * 8];
            const s8v a1 = *(const s8v*)&hfullA[16 + mrow][kt * 32 + kgrp * 8];
            const s8v bf = pW[((size_t)w * 16 + kt) * 64 + lane];
            p0 = mfma16(a0, bf, p0);
            p1 = mfma16(a1, bf, p1);
        }
        // write h(s) into xcat upper (next step's recurrent input)
        #pragma unroll
        for (int r = 0; r < 4; ++r) {
            xcat[kgrp * 4 + r][128 + w * 16 + mrow]      = f2b(p0[r]);
            xcat[16 + kgrp * 4 + r][128 + w * 16 + mrow] = f2b(p1[r]);
        }
        __syncthreads();   // xcat upper ready

        // ---- publish h(s) to downstream ring ----
        if (l < NLAYER - 1) {
            const ull v0 = *(const ull*)&xcat[cr][128 + cq];
            const ull v1 = *(const ull*)&xcat[cr][128 + cq + 4];
            ull* rb = ring + (((size_t)l * NCHUNK + chunk) * RINGD
                              + (s & (RINGD - 1))) * SLOT_ULL
                           + cr * 32 + (tid & 15) * 2;
            __hip_atomic_store(rb,     v0, __ATOMIC_RELAXED, __HIP_MEMORY_SCOPE_AGENT);
            __hip_atomic_store(rb + 1, v1, __ATOMIC_RELAXED, __HIP_MEMORY_SCOPE_AGENT);
            __syncthreads();   // drains all waves' ring stores (vmcnt at barrier)
            if (tid == 0)
                __hip_atomic_store(&hfl[l * NCHUNK + chunk], (unsigned)(s + 1),
                                   __ATOMIC_RELEASE, __HIP_MEMORY_SCOPE_AGENT);
        }

        // ---- FC head (decode, last layer): out = sigmoid(h5) @ Wfc^T + bfc ----
        if (l == NLAYER - 1 && s >= SEQT) {
            for (int i = tid; i < 32 * PROJ; i += 512) {
                const int r = i >> 7, c = i & 127;
                hfullA[r][c] = f2b(sigf(b2f(xcat[r][128 + c])));
            }
            __syncthreads();
            const float bv = bfc[w * 16 + mrow];
            f4v f0 = (f4v){bv, bv, bv, bv};
            f4v f1 = (f4v){bv, bv, bv, bv};
            #pragma unroll
            for (int kt = 0; kt < 4; ++kt) {
                const s8v a0 = *(const s8v*)&hfullA[mrow][kt * 32 + kgrp * 8];
                const s8v a1 = *(const s8v*)&hfullA[16 + mrow][kt * 32 + kgrp * 8];
                const s8v bf = fW[((size_t)w * 4 + kt) * 64 + lane];
                f0 = mfma16(a0, bf, f0);
                f1 = mfma16(a1, bf, f1);
            }
            const int td = s - SEQT;
            #pragma unroll
            for (int r = 0; r < 4; ++r) {
                out[(((size_t)(bb + kgrp * 4 + r)) * DSTEPS + td) * PROJ + w * 16 + mrow]      = f0[r];
                out[(((size_t)(bb + 16 + kgrp * 4 + r)) * DSTEPS + td) * PROJ + w * 16 + mrow] = f1[r];
            }
            __syncthreads();   // hfullA reuse guard before next step's pointwise
        }
    }
}

extern "C" void kernel_launch(void* const* d_in, const int* in_sizes, int n_in,
                              void* d_out, int out_size, void* d_ws, size_t ws_size,
                              hipStream_t stream)
{
    const float* x    = (const float*)d_in[0];
    const float* Wih  = (const float*)d_in[1];
    const float* Whh  = (const float*)d_in[2];
    const float* bih  = (const float*)d_in[3];
    const float* bhh  = (const float*)d_in[4];
    const float* Whr  = (const float*)d_in[5];
    const float* Wfc  = (const float*)d_in[6];
    const float* bfcv = (const float*)d_in[7];

    char* ws = (char*)d_ws;
    size_t off = 0;
    auto alloc = [&](size_t b) { char* p = ws + off; off += (b + 255) & ~(size_t)255; return p; };
    unsigned short* gB  = (unsigned short*)alloc((size_t)GFRAGS * 16);
    unsigned short* pB  = (unsigned short*)alloc((size_t)PFRAGS * 16);
    unsigned short* fB  = (unsigned short*)alloc((size_t)FFRAGS * 16);
    float* bsum         = (float*)alloc((size_t)NLAYER * NG * 4);
    float* bfc          = (float*)alloc((size_t)PROJ * 4);
    unsigned int* flags = (unsigned int*)alloc((size_t)NFLAGS * 4);
    ull* ring           = (ull*)alloc(RING_ULL * 8);
    if (off > ws_size) return;  // workspace too small; fail validation cleanly

    const int total = GFRAGS + PFRAGS + FFRAGS + NLAYER * NG + PROJ + NFLAGS;
    lstm_prepack<<<(total + 255) / 256, 256, 0, stream>>>(
        Wih, Whh, bih, bhh, Whr, Wfc, bfcv, gB, pB, fB, bsum, bfc, flags);
    lstm_main<<<96, 512, 0, stream>>>(
        x, gB, pB, fB, bsum, bfc, flags, ring, (float*)d_out);
}

// Round 4
// 26945.050 us; speedup vs baseline: 4.1833x; 1.1865x over previous
//
#include <hip/hip_runtime.h>

typedef short s8v __attribute__((ext_vector_type(8)));
typedef float f4v __attribute__((ext_vector_type(4)));
typedef unsigned long long ull;

#define NLAYER 6
#define HID    512
#define PROJ   128
#define SEQT   512
#define BATCH  512
#define DSTEPS 32
#define TOTS   (SEQT + DSTEPS)   // 544
#define NG     2048              // 4*H
#define BC     32                // batch rows per WG
#define NCHUNK (BATCH / BC)      // 16
#define RINGD  32                // ring depth (steps)

// packed fragment counts (each fragment = 64 lanes * 16B = 1 KiB)
#define GFRAGS (NLAYER * 128 * 8 * 64)   // gates: [l][ntile=128][ktile=8][lane]
#define PFRAGS (NLAYER * 8 * 16 * 64)    // proj : [l][ntile=8][ktile=16][lane]
#define FFRAGS (8 * 4 * 64)              // fc   : [ntile=8][ktile=4][lane]
#define NFLAGS (2 * 5 * NCHUNK)          // hflag[5][16] then aflag[5][16]
#define SLOT_ULL 1024                    // 32*128 bf16 = 8 KB = 1024 ull
#define RING_ULL ((size_t)5 * NCHUNK * RINGD * SLOT_ULL)

static __device__ __forceinline__ unsigned short f2b(float f) {
    union { float f; unsigned int u; } v; v.f = f;
    unsigned int r = v.u + 0x7fffu + ((v.u >> 16) & 1u);  // RNE
    return (unsigned short)(r >> 16);
}
static __device__ __forceinline__ float b2f(unsigned short s) {
    union { float f; unsigned int u; } v; v.u = ((unsigned int)s) << 16;
    return v.f;
}
static __device__ __forceinline__ float sigf(float x) {
    x = fminf(fmaxf(x, -30.f), 30.f);
    return 1.f / (1.f + __expf(-x));
}
static __device__ __forceinline__ float tanh_fast(float x) {
    x = fminf(fmaxf(x, -15.f), 15.f);
    float t = __expf(-2.f * x);
    return (1.f - t) / (1.f + t);
}
static __device__ __forceinline__ f4v mfma16(s8v a, s8v b, f4v c) {
    return __builtin_amdgcn_mfma_f32_16x16x32_bf16(a, b, c, 0, 0, 0);
}

// ---------------------------------------------------------------------------
// Prepack: fp32 weights -> bf16 MFMA B-fragment-linear layout, bias sum,
// zero sync flags. (identical fragment layout to rounds 1-3, which passed)
// ---------------------------------------------------------------------------
__global__ __launch_bounds__(256) void lstm_prepack(
    const float* __restrict__ Wih, const float* __restrict__ Whh,
    const float* __restrict__ bih, const float* __restrict__ bhh,
    const float* __restrict__ Whr, const float* __restrict__ Wfc,
    const float* __restrict__ bfcin,
    unsigned short* __restrict__ gB, unsigned short* __restrict__ pB,
    unsigned short* __restrict__ fB, float* __restrict__ bsum,
    float* __restrict__ bfc, unsigned int* __restrict__ flags)
{
    int tid = blockIdx.x * 256 + threadIdx.x;

    if (tid < GFRAGS) {  // gates: cat(Wih, Whh) over K=256
        const int lane = tid & 63;
        int rest = tid >> 6;
        const int kt = rest & 7;   rest >>= 3;
        const int nt = rest & 127; rest >>= 7;
        const int l  = rest;
        const int n  = nt * 16 + (lane & 15);
        const int kb = kt * 32 + (lane >> 4) * 8;
        const float* src = (kb < 128)
            ? (Wih + ((size_t)l * NG + n) * PROJ + kb)
            : (Whh + ((size_t)l * NG + n) * PROJ + (kb - 128));
        unsigned short o[8];
        #pragma unroll
        for (int e = 0; e < 8; ++e) o[e] = f2b(src[e]);
        *(s8v*)(gB + (size_t)tid * 8) = *(const s8v*)o;
        return;
    }
    tid -= GFRAGS;
    if (tid < PFRAGS) {  // proj: Whr (p x 512), B[k][p] = Whr[p][k]
        const int lane = tid & 63;
        int rest = tid >> 6;
        const int kt = rest & 15; rest >>= 4;
        const int nt = rest & 7;  rest >>= 3;
        const int l  = rest;
        const int n  = nt * 16 + (lane & 15);
        const int kb = kt * 32 + (lane >> 4) * 8;
        const float* src = Whr + ((size_t)l * PROJ + n) * HID + kb;
        unsigned short o[8];
        #pragma unroll
        for (int e = 0; e < 8; ++e) o[e] = f2b(src[e]);
        *(s8v*)(pB + (size_t)tid * 8) = *(const s8v*)o;
        return;
    }
    tid -= PFRAGS;
    if (tid < FFRAGS) {  // fc: Wfc (128x128)
        const int lane = tid & 63;
        int rest = tid >> 6;
        const int kt = rest & 3;
        const int nt = rest >> 2;
        const int n  = nt * 16 + (lane & 15);
        const int kb = kt * 32 + (lane >> 4) * 8;
        const float* src = Wfc + (size_t)n * PROJ + kb;
        unsigned short o[8];
        #pragma unroll
        for (int e = 0; e < 8; ++e) o[e] = f2b(src[e]);
        *(s8v*)(fB + (size_t)tid * 8) = *(const s8v*)o;
        return;
    }
    tid -= FFRAGS;
    if (tid < NLAYER * NG) { bsum[tid] = bih[tid] + bhh[tid]; return; }
    tid -= NLAYER * NG;
    if (tid < PROJ) { bfc[tid] = bfcin[tid]; return; }
    tid -= PROJ;
    if (tid < NFLAGS) { flags[tid] = 0u; return; }
}

// ---------------------------------------------------------------------------
// Main: 96 blocks x 1024 threads (16 waves), one (layer, batch-chunk) per
// block. 16 waves halve each wave's fragment-load chain (64 x 1KiB) and acc
// (16 f4v) vs the 8-wave version, and give 4 waves/SIMD of latency hiding.
// XCD-locality map: g = (b%8)*12 + b/8, l = g/16, chunk = g%16 -> each XCD
// hosts 12 WGs spanning <=2 layers (<=2.3 MiB weights). Layers pipeline via
// ring buffers + flags (relaxed agent atomics for data; release on flag).
// Wave w: gates j-slice [w*32,w*32+32) all 4 gates; proj p-tile w&7, m-half w>>3.
// ---------------------------------------------------------------------------
__global__ __launch_bounds__(1024) void lstm_main(
    const float* __restrict__ x,               // [512][512][128] fp32
    const unsigned short* __restrict__ gB,
    const unsigned short* __restrict__ pB,
    const unsigned short* __restrict__ fB,
    const float* __restrict__ bsum,            // [6][2048]
    const float* __restrict__ bfc,             // [128]
    unsigned int* __restrict__ flags,          // [hflag 5*16][aflag 5*16]
    ull* __restrict__ ring,                    // [5][16][RINGD][1024]
    float* __restrict__ out)                   // [512][32][128] fp32
{
    const int g0    = (blockIdx.x & 7) * 12 + (blockIdx.x >> 3);
    const int l     = g0 >> 4;
    const int chunk = g0 & 15;
    const int bb    = chunk * BC;

    __shared__ __align__(16) unsigned short xcat[32][264];    // A=[xt | h_rec], K=256
    __shared__ __align__(16) unsigned short hfullA[32][520];  // h_full bf16 (proj A)
    __shared__ float biasS[NG];

    const int tid  = threadIdx.x;
    const int lane = tid & 63;
    const int w    = tid >> 6;          // wave 0..15
    const int mrow = lane & 15;
    const int kgrp = lane >> 4;
    const int pt   = w & 7;             // proj/fc p-tile
    const int mh   = w >> 3;            // proj/fc m-half
    const int cr   = tid >> 5;          // copy row 0..31
    const int cc   = (tid & 31) * 4;    // copy col (shorts), step 4 (one ull)

    for (int i = tid; i < 32 * 264; i += 1024) ((unsigned short*)xcat)[i] = 0;
    for (int i = tid; i < NG; i += 1024) biasS[i] = bsum[l * NG + i];

    const s8v* gW = (const s8v*)gB + (size_t)l * 128 * 8 * 64;
    const s8v* pW = (const s8v*)pB + (size_t)l * 8 * 16 * 64;
    const s8v* fW = (const s8v*)fB;
    unsigned int* hfl = flags;                 // [5][16]
    unsigned int* afl = flags + 5 * NCHUNK;    // [5][16]

    // c-state in registers: wave w owns j = w*32 + jt*16 + mrow,
    // m = mt*16 + kgrp*4 + r
    f4v cst[2][2];
    #pragma unroll
    for (int jt = 0; jt < 2; ++jt)
      #pragma unroll
      for (int mt = 0; mt < 2; ++mt)
        cst[jt][mt] = (f4v){0.f, 0.f, 0.f, 0.f};

    __syncthreads();

    #pragma unroll 1
    for (int s = 0; s < TOTS; ++s) {
        // ---- polls (upstream data ready; downstream ring slot free) ----
        if (tid == 0) {
            if (l > 0) {
                while (__hip_atomic_load(&hfl[(l - 1) * NCHUNK + chunk],
                        __ATOMIC_RELAXED, __HIP_MEMORY_SCOPE_AGENT) < (unsigned)(s + 1))
                    __builtin_amdgcn_s_sleep(2);
            }
            if (l < NLAYER - 1 && s >= RINGD) {
                while (__hip_atomic_load(&afl[l * NCHUNK + chunk],
                        __ATOMIC_RELAXED, __HIP_MEMORY_SCOPE_AGENT) < (unsigned)(s - RINGD + 1))
                    __builtin_amdgcn_s_sleep(2);
            }
        }
        __syncthreads();

        // ---- input build (xcat lower half), one ull per thread ----
        if (l == 0) {
            if (s < SEQT) {
                const float* xp = x + (((size_t)(bb + cr)) * SEQT + s) * PROJ + cc;
                const float4 v = *(const float4*)xp;
                unsigned short o[4];
                o[0] = f2b(v.x); o[1] = f2b(v.y); o[2] = f2b(v.z); o[3] = f2b(v.w);
                *(ull*)&xcat[cr][cc] = *(const ull*)o;
            } else {
                *(ull*)&xcat[cr][cc] = 0ull;
            }
        } else {
            const ull* rb = ring + (((size_t)(l - 1) * NCHUNK + chunk) * RINGD
                                    + (s & (RINGD - 1))) * SLOT_ULL
                                 + cr * 32 + (tid & 31);
            const ull v = __hip_atomic_load(rb, __ATOMIC_RELAXED, __HIP_MEMORY_SCOPE_AGENT);
            *(ull*)&xcat[cr][cc] = v;
        }
        __syncthreads();   // xcat ready (drains each wave's loads -> safe to ack)
        if (tid == 0 && l > 0)
            __hip_atomic_store(&afl[(l - 1) * NCHUNK + chunk], (unsigned)(s + 1),
                               __ATOMIC_RELAXED, __HIP_MEMORY_SCOPE_AGENT);

        // ---- gates GEMM: [32 x 256] @ [256 x 2048], wave w -> j-slice w*32 ----
        f4v acc[4][2][2];
        #pragma unroll
        for (int gg = 0; gg < 4; ++gg)
          #pragma unroll
          for (int jt = 0; jt < 2; ++jt) {
            const float b = biasS[gg * HID + w * 32 + jt * 16 + mrow];
            acc[gg][jt][0] = (f4v){b, b, b, b};
            acc[gg][jt][1] = (f4v){b, b, b, b};
          }
        #pragma unroll
        for (int kt = 0; kt < 8; ++kt) {
            const s8v a0 = *(const s8v*)&xcat[mrow][kt * 32 + kgrp * 8];
            const s8v a1 = *(const s8v*)&xcat[16 + mrow][kt * 32 + kgrp * 8];
            #pragma unroll
            for (int gg = 0; gg < 4; ++gg)
              #pragma unroll
              for (int jt = 0; jt < 2; ++jt) {
                const s8v bf = gW[(((size_t)(gg * 32 + w * 2 + jt)) * 8 + kt) * 64 + lane];
                acc[gg][jt][0] = mfma16(a0, bf, acc[gg][jt][0]);
                acc[gg][jt][1] = mfma16(a1, bf, acc[gg][jt][1]);
              }
        }

        // ---- pointwise: c in regs, h_full -> LDS bf16 ----
        #pragma unroll
        for (int jt = 0; jt < 2; ++jt)
          #pragma unroll
          for (int mt = 0; mt < 2; ++mt) {
            f4v cv = cst[jt][mt];
            #pragma unroll
            for (int r = 0; r < 4; ++r) {
                const float iv = acc[0][jt][mt][r];
                const float fv = acc[1][jt][mt][r];
                const float gv = acc[2][jt][mt][r];
                const float ov = acc[3][jt][mt][r];
                const float cn = sigf(fv) * cv[r] + sigf(iv) * tanh_fast(gv);
                const float hf = sigf(ov) * tanh_fast(cn);
                cv[r] = cn;
                hfullA[mt * 16 + kgrp * 4 + r][w * 32 + jt * 16 + mrow] = f2b(hf);
            }
            cst[jt][mt] = cv;
          }
        __syncthreads();   // hfullA ready; xcat reads done

        // ---- proj GEMM: [32 x 512] @ [512 x 128]; wave -> (p-tile pt, m-half mh) ----
        f4v p0 = (f4v){0.f, 0.f, 0.f, 0.f};
        #pragma unroll
        for (int kt = 0; kt < 16; ++kt) {
            const s8v a  = *(const s8v*)&hfullA[mh * 16 + mrow][kt * 32 + kgrp * 8];
            const s8v bf = pW[((size_t)pt * 16 + kt) * 64 + lane];
            p0 = mfma16(a, bf, p0);
        }
        // write h(s) into xcat upper (next step's recurrent input)
        #pragma unroll
        for (int r = 0; r < 4; ++r)
            xcat[mh * 16 + kgrp * 4 + r][128 + pt * 16 + mrow] = f2b(p0[r]);
        __syncthreads();   // xcat upper ready

        // ---- publish h(s) to downstream ring, one ull per thread ----
        if (l < NLAYER - 1) {
            const ull v = *(const ull*)&xcat[cr][128 + cc];
            ull* rb = ring + (((size_t)l * NCHUNK + chunk) * RINGD
                              + (s & (RINGD - 1))) * SLOT_ULL
                           + cr * 32 + (tid & 31);
            __hip_atomic_store(rb, v, __ATOMIC_RELAXED, __HIP_MEMORY_SCOPE_AGENT);
            __syncthreads();   // drains all waves' ring stores (vmcnt at barrier)
            if (tid == 0)
                __hip_atomic_store(&hfl[l * NCHUNK + chunk], (unsigned)(s + 1),
                                   __ATOMIC_RELEASE, __HIP_MEMORY_SCOPE_AGENT);
        }

        // ---- FC head (decode, last layer): out = sigmoid(h5) @ Wfc^T + bfc ----
        if (l == NLAYER - 1 && s >= SEQT) {
            for (int i = tid; i < 32 * PROJ; i += 1024) {
                const int r = i >> 7, c = i & 127;
                hfullA[r][c] = f2b(sigf(b2f(xcat[r][128 + c])));
            }
            __syncthreads();
            const float bv = bfc[pt * 16 + mrow];
            f4v f0 = (f4v){bv, bv, bv, bv};
            #pragma unroll
            for (int kt = 0; kt < 4; ++kt) {
                const s8v a  = *(const s8v*)&hfullA[mh * 16 + mrow][kt * 32 + kgrp * 8];
                const s8v bf = fW[((size_t)pt * 4 + kt) * 64 + lane];
                f0 = mfma16(a, bf, f0);
            }
            const int td = s - SEQT;
            #pragma unroll
            for (int r = 0; r < 4; ++r)
                out[(((size_t)(bb + mh * 16 + kgrp * 4 + r)) * DSTEPS + td) * PROJ
                    + pt * 16 + mrow] = f0[r];
            __syncthreads();   // hfullA reuse guard before next step's pointwise
        }
    }
}

extern "C" void kernel_launch(void* const* d_in, const int* in_sizes, int n_in,
                              void* d_out, int out_size, void* d_ws, size_t ws_size,
                              hipStream_t stream)
{
    const float* x    = (const float*)d_in[0];
    const float* Wih  = (const float*)d_in[1];
    const float* Whh  = (const float*)d_in[2];
    const float* bih  = (const float*)d_in[3];
    const float* bhh  = (const float*)d_in[4];
    const float* Whr  = (const float*)d_in[5];
    const float* Wfc  = (const float*)d_in[6];
    const float* bfcv = (const float*)d_in[7];

    char* ws = (char*)d_ws;
    size_t off = 0;
    auto alloc = [&](size_t b) { char* p = ws + off; off += (b + 255) & ~(size_t)255; return p; };
    unsigned short* gB  = (unsigned short*)alloc((size_t)GFRAGS * 16);
    unsigned short* pB  = (unsigned short*)alloc((size_t)PFRAGS * 16);
    unsigned short* fB  = (unsigned short*)alloc((size_t)FFRAGS * 16);
    float* bsum         = (float*)alloc((size_t)NLAYER * NG * 4);
    float* bfc          = (float*)alloc((size_t)PROJ * 4);
    unsigned int* flags = (unsigned int*)alloc((size_t)NFLAGS * 4);
    ull* ring           = (ull*)alloc(RING_ULL * 8);
    if (off > ws_size) return;  // workspace too small; fail validation cleanly

    const int total = GFRAGS + PFRAGS + FFRAGS + NLAYER * NG + PROJ + NFLAGS;
    lstm_prepack<<<(total + 255) / 256, 256, 0, stream>>>(
        Wih, Whh, bih, bhh, Whr, Wfc, bfcv, gB, pB, fB, bsum, bfc, flags);
    lstm_main<<<96, 1024, 0, stream>>>(
        x, gB, pB, fB, bsum, bfc, flags, ring, (float*)d_out);
}

// Round 5
// 11575.829 us; speedup vs baseline: 9.7374x; 2.3277x over previous
//
#include <hip/hip_runtime.h>

typedef short s8v __attribute__((ext_vector_type(8)));
typedef float f4v __attribute__((ext_vector_type(4)));
typedef unsigned long long ull;

#define NLAYER 6
#define HID    512
#define PROJ   128
#define SEQT   512
#define BATCH  512
#define DSTEPS 32
#define TOTS   (SEQT + DSTEPS)   // 544
#define NG     2048              // 4*H
#define BC     64                // batch rows per unit
#define NCHUNK (BATCH / BC)      // 8
#define NUNIT  (NLAYER * NCHUNK) // 48
#define RINGD  8                 // hy ring depth (steps)

// packed fragment counts (each fragment = 64 lanes * 16B = 1 KiB)
#define GFRAGS (NLAYER * 128 * 8 * 64)   // gates: [l][ntile=128][ktile=8][lane]
#define PFRAGS (NLAYER * 8 * 16 * 64)    // proj : [l][ntile=8][ktile=16][lane]
#define FFRAGS (8 * 4 * 64)              // fc   : [ntile=8][ktile=4][lane]
#define NFLAGS (2 * NUNIT)               // ubA[48] then ubB[48]

#define HX_ULL 8192                      // per-unit h_full exchange [64][512] bf16
#define HY_SLOT_ULL 2048                 // per-unit h slot [64][128] bf16

static __device__ __forceinline__ unsigned short f2b(float f) {
    union { float f; unsigned int u; } v; v.f = f;
    unsigned int r = v.u + 0x7fffu + ((v.u >> 16) & 1u);  // RNE
    return (unsigned short)(r >> 16);
}
static __device__ __forceinline__ float b2f(unsigned short s) {
    union { float f; unsigned int u; } v; v.u = ((unsigned int)s) << 16;
    return v.f;
}
static __device__ __forceinline__ float sigf(float x) {
    x = fminf(fmaxf(x, -30.f), 30.f);
    return 1.f / (1.f + __expf(-x));
}
static __device__ __forceinline__ float tanh_fast(float x) {
    x = fminf(fmaxf(x, -15.f), 15.f);
    float t = __expf(-2.f * x);
    return (1.f - t) / (1.f + t);
}
static __device__ __forceinline__ f4v mfma16(s8v a, s8v b, f4v c) {
    return __builtin_amdgcn_mfma_f32_16x16x32_bf16(a, b, c, 0, 0, 0);
}
static __device__ __forceinline__ ull ald(const ull* p) {
    return __hip_atomic_load(p, __ATOMIC_RELAXED, __HIP_MEMORY_SCOPE_AGENT);
}
static __device__ __forceinline__ void ast(ull* p, ull v) {
    __hip_atomic_store(p, v, __ATOMIC_RELAXED, __HIP_MEMORY_SCOPE_AGENT);
}
static __device__ __forceinline__ void spin_ge(unsigned* p, unsigned v) {
    while (__hip_atomic_load(p, __ATOMIC_RELAXED, __HIP_MEMORY_SCOPE_AGENT) < v)
        __builtin_amdgcn_s_sleep(2);
}

// ---------------------------------------------------------------------------
// Prepack: fp32 weights -> bf16 MFMA B-fragment-linear layout, bias sum,
// zero sync counters. (identical fragment layout to rounds 1-4, which passed)
// ---------------------------------------------------------------------------
__global__ __launch_bounds__(256) void lstm_prepack(
    const float* __restrict__ Wih, const float* __restrict__ Whh,
    const float* __restrict__ bih, const float* __restrict__ bhh,
    const float* __restrict__ Whr, const float* __restrict__ Wfc,
    const float* __restrict__ bfcin,
    unsigned short* __restrict__ gB, unsigned short* __restrict__ pB,
    unsigned short* __restrict__ fB, float* __restrict__ bsum,
    float* __restrict__ bfc, unsigned int* __restrict__ flags)
{
    int tid = blockIdx.x * 256 + threadIdx.x;

    if (tid < GFRAGS) {  // gates: cat(Wih, Whh) over K=256
        const int lane = tid & 63;
        int rest = tid >> 6;
        const int kt = rest & 7;   rest >>= 3;
        const int nt = rest & 127; rest >>= 7;
        const int l  = rest;
        const int n  = nt * 16 + (lane & 15);
        const int kb = kt * 32 + (lane >> 4) * 8;
        const float* src = (kb < 128)
            ? (Wih + ((size_t)l * NG + n) * PROJ + kb)
            : (Whh + ((size_t)l * NG + n) * PROJ + (kb - 128));
        unsigned short o[8];
        #pragma unroll
        for (int e = 0; e < 8; ++e) o[e] = f2b(src[e]);
        *(s8v*)(gB + (size_t)tid * 8) = *(const s8v*)o;
        return;
    }
    tid -= GFRAGS;
    if (tid < PFRAGS) {  // proj: Whr (p x 512), B[k][p] = Whr[p][k]
        const int lane = tid & 63;
        int rest = tid >> 6;
        const int kt = rest & 15; rest >>= 4;
        const int nt = rest & 7;  rest >>= 3;
        const int l  = rest;
        const int n  = nt * 16 + (lane & 15);
        const int kb = kt * 32 + (lane >> 4) * 8;
        const float* src = Whr + ((size_t)l * PROJ + n) * HID + kb;
        unsigned short o[8];
        #pragma unroll
        for (int e = 0; e < 8; ++e) o[e] = f2b(src[e]);
        *(s8v*)(pB + (size_t)tid * 8) = *(const s8v*)o;
        return;
    }
    tid -= PFRAGS;
    if (tid < FFRAGS) {  // fc: Wfc (128x128)
        const int lane = tid & 63;
        int rest = tid >> 6;
        const int kt = rest & 3;
        const int nt = rest >> 2;
        const int n  = nt * 16 + (lane & 15);
        const int kb = kt * 32 + (lane >> 4) * 8;
        const float* src = Wfc + (size_t)n * PROJ + kb;
        unsigned short o[8];
        #pragma unroll
        for (int e = 0; e < 8; ++e) o[e] = f2b(src[e]);
        *(s8v*)(fB + (size_t)tid * 8) = *(const s8v*)o;
        return;
    }
    tid -= FFRAGS;
    if (tid < NLAYER * NG) { bsum[tid] = bih[tid] + bhh[tid]; return; }
    tid -= NLAYER * NG;
    if (tid < PROJ) { bfc[tid] = bfcin[tid]; return; }
    tid -= PROJ;
    if (tid < NFLAGS) { flags[tid] = 0u; return; }
}

// ---------------------------------------------------------------------------
// Main: 192 blocks x 512 threads. Unit = (layer l, 64-row chunk c): 4 WGs
// (sub 0..3), 32 waves. Wave u = sub*8+w holds its gates weight slab (4 gates
// x 16 j x 256 k = 32 KB) in 128 VGPRs -- loaded ONCE, reused all 544 steps.
// Proj slab (p-slice 32 x 512) in LDS per WG. Per step, h_full ([64][512])
// and h ([64][128]) are exchanged between the 4 WGs via global hx / hy ring
// with monotonic-counter barriers (ubA/ubB, release add + relaxed spin --
// the sync pattern validated in rounds 2-4). c-state in registers.
// Placement: blockIdx%8 = XCD; a unit's 4 subs land on one XCD.
// ---------------------------------------------------------------------------
__global__ __launch_bounds__(512, 2) void lstm_main(
    const float* __restrict__ x,               // [512][512][128] fp32
    const unsigned short* __restrict__ gB,
    const unsigned short* __restrict__ pB,
    const unsigned short* __restrict__ fB,
    const float* __restrict__ bsum,            // [6][2048]
    const float* __restrict__ bfc,             // [128]
    unsigned int* __restrict__ flags,          // ubA[48] ubB[48]
    ull* __restrict__ hxbuf,                   // [48][8192]
    ull* __restrict__ hybuf,                   // [48][RINGD][2048]
    float* __restrict__ out)                   // [512][32][128] fp32
{
    const int xcd  = blockIdx.x & 7;
    const int slot = blockIdx.x >> 3;      // 0..23
    const int uo   = slot >> 2;            // 0..5
    const int sub  = slot & 3;
    const int unit = xcd * 6 + uo;         // 0..47
    const int l    = unit >> 3;
    const int c    = unit & 7;
    const int bb   = c * BC;

    __shared__ __align__(16) unsigned short xcat[64][264];    // A=[xt | h_rec], K=256
    __shared__ __align__(16) unsigned short hfullA[64][520];  // h_full bf16 (proj A)
    __shared__ __align__(16) unsigned short pslab[2 * 16 * 64 * 8];  // 32 KB proj B frags

    const int tid  = threadIdx.x;
    const int lane = tid & 63;
    const int w    = tid >> 6;            // wave 0..7
    const int u    = sub * 8 + w;         // unit-wave 0..31
    const int mrow = lane & 15;
    const int kgrp = lane >> 4;

    for (int i = tid; i < 64 * 264; i += 512) ((unsigned short*)xcat)[i] = 0;

    const s8v* gfrag = (const s8v*)gB;
    const s8v* pfrag = (const s8v*)pB;
    const s8v* ffrag = (const s8v*)fB;

    // ---- persistent gates weights: 32 fragments = 128 VGPRs ----
    s8v wreg[4][8];
    #pragma unroll
    for (int g = 0; g < 4; ++g)
      #pragma unroll
      for (int kt = 0; kt < 8; ++kt)
        wreg[g][kt] = gfrag[(((size_t)l * 128 + g * 32 + u) * 8 + kt) * 64 + lane];

    float bias[4];
    #pragma unroll
    for (int g = 0; g < 4; ++g)
        bias[g] = bsum[l * NG + g * HID + u * 16 + mrow];

    // ---- proj slab -> LDS (once) ----
    for (int i = tid; i < 2048; i += 512) {
        const int nt = i >> 10, rem = i & 1023, kt = rem >> 6, ln = rem & 63;
        ((s8v*)pslab)[i] = pfrag[(((size_t)l * 8 + sub * 2 + nt) * 16 + kt) * 64 + ln];
    }

    f4v cst[4];
    #pragma unroll
    for (int mt = 0; mt < 4; ++mt) cst[mt] = (f4v){0.f, 0.f, 0.f, 0.f};

    unsigned int* ubA = flags;
    unsigned int* ubB = flags + NUNIT;
    ull* hx  = hxbuf + (size_t)unit * HX_ULL;
    ull* hyo = hybuf + (size_t)unit * RINGD * HY_SLOT_ULL;
    const ull* hyup = hybuf + (size_t)(unit - NCHUNK) * RINGD * HY_SLOT_ULL;

    __syncthreads();

    #pragma unroll 1
    for (int s = 0; s < TOTS; ++s) {
        // ---- 1: xcat lower (input) ----
        if (l > 0) {
            if (tid == 0) spin_ge(&ubB[unit - NCHUNK], 4u * (s + 1));
            __syncthreads();                                           // B1
            const ull* src = hyup + (size_t)(s & (RINGD - 1)) * HY_SLOT_ULL;
            for (int i = tid; i < 2048; i += 512)
                *(ull*)&xcat[i >> 5][(i & 31) * 4] = ald(src + i);
        } else if (s < SEQT) {
            for (int i = tid; i < 2048; i += 512) {
                const int m = i >> 5, pq = i & 31;
                const float4 v = *(const float4*)(x + (((size_t)(bb + m)) * SEQT + s) * PROJ + pq * 4);
                unsigned short o[4];
                o[0] = f2b(v.x); o[1] = f2b(v.y); o[2] = f2b(v.z); o[3] = f2b(v.w);
                *(ull*)&xcat[m][pq * 4] = *(const ull*)o;
            }
        } else if (s == SEQT) {
            for (int i = tid; i < 2048; i += 512)
                *(ull*)&xcat[i >> 5][(i & 31) * 4] = 0ull;
        }
        __syncthreads();                                               // B2

        // ---- 2: gates GEMM (weights in regs) + pointwise, mt-outer ----
        #pragma unroll
        for (int mt = 0; mt < 4; ++mt) {
            f4v a0 = (f4v){bias[0], bias[0], bias[0], bias[0]};
            f4v a1 = (f4v){bias[1], bias[1], bias[1], bias[1]};
            f4v a2 = (f4v){bias[2], bias[2], bias[2], bias[2]};
            f4v a3 = (f4v){bias[3], bias[3], bias[3], bias[3]};
            #pragma unroll
            for (int kt = 0; kt < 8; ++kt) {
                const s8v a = *(const s8v*)&xcat[mt * 16 + mrow][kt * 32 + kgrp * 8];
                a0 = mfma16(a, wreg[0][kt], a0);
                a1 = mfma16(a, wreg[1][kt], a1);
                a2 = mfma16(a, wreg[2][kt], a2);
                a3 = mfma16(a, wreg[3][kt], a3);
            }
            f4v cv = cst[mt];
            #pragma unroll
            for (int r = 0; r < 4; ++r) {
                const float cn = sigf(a1[r]) * cv[r] + sigf(a0[r]) * tanh_fast(a2[r]);
                const float hf = sigf(a3[r]) * tanh_fast(cn);
                cv[r] = cn;
                hfullA[mt * 16 + kgrp * 4 + r][u * 16 + mrow] = f2b(hf);
            }
            cst[mt] = cv;
        }
        __syncthreads();                                               // B3

        // ---- 3: copy-out local j-quarter -> hx ----
        for (int i = tid; i < 2048; i += 512) {
            const int m = i >> 5, jq = i & 31;
            ast(hx + m * 128 + sub * 32 + jq, *(const ull*)&hfullA[m][sub * 128 + jq * 4]);
        }
        __syncthreads();                                               // B4
        if (tid == 0) {
            __hip_atomic_fetch_add(&ubA[unit], 1u, __ATOMIC_RELEASE, __HIP_MEMORY_SCOPE_AGENT);
            spin_ge(&ubA[unit], 4u * (s + 1));
            if (l < NLAYER - 1 && s >= RINGD)
                spin_ge(&ubA[unit + NCHUNK], 4u * (s - RINGD + 1));    // hy slot reuse guard
        }
        __syncthreads();                                               // B5
        // ---- 4: copy-in other 3 j-quarters ----
        for (int i = tid; i < 6144; i += 512) {
            const int q0 = i >> 11, q = q0 + (q0 >= sub);
            const int rem = i & 2047, m = rem >> 5, jq = rem & 31;
            *(ull*)&hfullA[m][q * 128 + jq * 4] = ald(hx + m * 128 + q * 32 + jq);
        }
        __syncthreads();                                               // B6

        // ---- 5: proj GEMM (B slab in LDS); wave -> (p-tile sub*2+(w&1), mt=w>>1) ----
        {
            const int ntl = w & 1, mt = w >> 1;
            f4v pacc = (f4v){0.f, 0.f, 0.f, 0.f};
            #pragma unroll
            for (int kt = 0; kt < 16; ++kt) {
                const s8v a  = *(const s8v*)&hfullA[mt * 16 + mrow][kt * 32 + kgrp * 8];
                const s8v bf = ((const s8v*)pslab)[(ntl * 16 + kt) * 64 + lane];
                pacc = mfma16(a, bf, pacc);
            }
            #pragma unroll
            for (int r = 0; r < 4; ++r)
                xcat[mt * 16 + kgrp * 4 + r][128 + (sub * 2 + ntl) * 16 + mrow] = f2b(pacc[r]);
        }
        __syncthreads();                                               // B7

        // ---- 6: copy-out p-slice -> hy[s%R]; barrier B; copy-in other 3 ----
        ull* hslot = hyo + (size_t)(s & (RINGD - 1)) * HY_SLOT_ULL;
        {
            const int m = tid >> 3, pq = tid & 7;
            ast(hslot + m * 32 + sub * 8 + pq, *(const ull*)&xcat[m][128 + sub * 32 + pq * 4]);
        }
        __syncthreads();                                               // B8
        if (tid == 0) {
            __hip_atomic_fetch_add(&ubB[unit], 1u, __ATOMIC_RELEASE, __HIP_MEMORY_SCOPE_AGENT);
            spin_ge(&ubB[unit], 4u * (s + 1));
        }
        __syncthreads();                                               // B9
        for (int i = tid; i < 1536; i += 512) {
            const int q0 = i >> 9, q = q0 + (q0 >= sub);
            const int rem = i & 511, m = rem >> 3, pq = rem & 7;
            *(ull*)&xcat[m][128 + q * 32 + pq * 4] = ald(hslot + m * 32 + q * 8 + pq);
        }

        // ---- 7: FC head (decode, last layer) ----
        if (l == NLAYER - 1 && s >= SEQT) {
            __syncthreads();
            for (int i = tid; i < 8192; i += 512)
                hfullA[i >> 7][i & 127] = f2b(sigf(b2f(xcat[i >> 7][128 + (i & 127)])));
            __syncthreads();
            const int mt = u >> 3, pt2 = u & 7;
            const float bv = bfc[pt2 * 16 + mrow];
            f4v facc = (f4v){bv, bv, bv, bv};
            #pragma unroll
            for (int kt = 0; kt < 4; ++kt) {
                const s8v a  = *(const s8v*)&hfullA[mt * 16 + mrow][kt * 32 + kgrp * 8];
                const s8v bf = ffrag[((size_t)pt2 * 4 + kt) * 64 + lane];
                facc = mfma16(a, bf, facc);
            }
            const int td = s - SEQT;
            #pragma unroll
            for (int r = 0; r < 4; ++r)
                out[(((size_t)(bb + mt * 16 + kgrp * 4 + r)) * DSTEPS + td) * PROJ
                    + pt2 * 16 + mrow] = facc[r];
        }
        __syncthreads();                                               // end-of-step
    }
}

extern "C" void kernel_launch(void* const* d_in, const int* in_sizes, int n_in,
                              void* d_out, int out_size, void* d_ws, size_t ws_size,
                              hipStream_t stream)
{
    const float* x    = (const float*)d_in[0];
    const float* Wih  = (const float*)d_in[1];
    const float* Whh  = (const float*)d_in[2];
    const float* bih  = (const float*)d_in[3];
    const float* bhh  = (const float*)d_in[4];
    const float* Whr  = (const float*)d_in[5];
    const float* Wfc  = (const float*)d_in[6];
    const float* bfcv = (const float*)d_in[7];

    char* ws = (char*)d_ws;
    size_t off = 0;
    auto alloc = [&](size_t b) { char* p = ws + off; off += (b + 255) & ~(size_t)255; return p; };
    unsigned short* gB  = (unsigned short*)alloc((size_t)GFRAGS * 16);
    unsigned short* pB  = (unsigned short*)alloc((size_t)PFRAGS * 16);
    unsigned short* fB  = (unsigned short*)alloc((size_t)FFRAGS * 16);
    float* bsum         = (float*)alloc((size_t)NLAYER * NG * 4);
    float* bfc          = (float*)alloc((size_t)PROJ * 4);
    unsigned int* flags = (unsigned int*)alloc((size_t)NFLAGS * 4);
    ull* hxbuf          = (ull*)alloc((size_t)NUNIT * HX_ULL * 8);
    ull* hybuf          = (ull*)alloc((size_t)NUNIT * RINGD * HY_SLOT_ULL * 8);
    if (off > ws_size) return;  // workspace too small; fail validation cleanly

    const int total = GFRAGS + PFRAGS + FFRAGS + NLAYER * NG + PROJ + NFLAGS;
    lstm_prepack<<<(total + 255) / 256, 256, 0, stream>>>(
        Wih, Whh, bih, bhh, Whr, Wfc, bfcv, gB, pB, fB, bsum, bfc, flags);
    lstm_main<<<NUNIT * 4, 512, 0, stream>>>(
        x, gB, pB, fB, bsum, bfc, flags, hxbuf, hybuf, (float*)d_out);
}

// Round 6
// 10618.772 us; speedup vs baseline: 10.6151x; 1.0901x over previous
//
#include <hip/hip_runtime.h>

typedef short s8v __attribute__((ext_vector_type(8)));
typedef float f4v __attribute__((ext_vector_type(4)));
typedef unsigned long long ull;

#define NLAYER 6
#define HID    512
#define PROJ   128
#define SEQT   512
#define BATCH  512
#define DSTEPS 32
#define TOTS   (SEQT + DSTEPS)   // 544
#define NG     2048              // 4*H
#define BC     64                // batch rows per unit
#define NCHUNK (BATCH / BC)      // 8
#define NUNIT  (NLAYER * NCHUNK) // 48
#define RINGP  4                 // partials ring depth (steps)
#define PP_FLOATS 8192           // one partial slab: [64][128] f32

// packed fragment counts (each fragment = 64 lanes * 16B = 1 KiB)
#define GFRAGS (NLAYER * 128 * 8 * 64)   // gates: [l][ntile=128][ktile=8][lane]
#define PFRAGS (NLAYER * 8 * 16 * 64)    // proj : [l][ntile=8][ktile=16][lane]
#define FFRAGS (8 * 4 * 64)              // fc   : [ntile=8][ktile=4][lane]
#define NFLAGS NUNIT                     // ub[48]

static __device__ __forceinline__ unsigned short f2b(float f) {
    union { float f; unsigned int u; } v; v.f = f;
    unsigned int r = v.u + 0x7fffu + ((v.u >> 16) & 1u);  // RNE
    return (unsigned short)(r >> 16);
}
static __device__ __forceinline__ float sigf(float x) {
    x = fminf(fmaxf(x, -30.f), 30.f);
    return 1.f / (1.f + __expf(-x));
}
static __device__ __forceinline__ float tanh_fast(float x) {
    x = fminf(fmaxf(x, -15.f), 15.f);
    float t = __expf(-2.f * x);
    return (1.f - t) / (1.f + t);
}
static __device__ __forceinline__ f4v mfma16(s8v a, s8v b, f4v c) {
    return __builtin_amdgcn_mfma_f32_16x16x32_bf16(a, b, c, 0, 0, 0);
}
static __device__ __forceinline__ ull ald(const ull* p) {
    return __hip_atomic_load(p, __ATOMIC_RELAXED, __HIP_MEMORY_SCOPE_AGENT);
}
static __device__ __forceinline__ void astf(float* p, float v) {
    __hip_atomic_store(p, v, __ATOMIC_RELAXED, __HIP_MEMORY_SCOPE_AGENT);
}
static __device__ __forceinline__ void spin_ge(unsigned* p, unsigned v) {
    while (__hip_atomic_load(p, __ATOMIC_RELAXED, __HIP_MEMORY_SCOPE_AGENT) < v)
        __builtin_amdgcn_s_sleep(2);
}
static __device__ __forceinline__ void upk(ull v, float& lo, float& hi) {
    union { ull u; float f[2]; } x; x.u = v; lo = x.f[0]; hi = x.f[1];
}

// ---------------------------------------------------------------------------
// Prepack: fp32 weights -> bf16 MFMA B-fragment-linear layout, bias sum,
// zero sync counters. (identical fragment layout to rounds 1-5, which passed)
// ---------------------------------------------------------------------------
__global__ __launch_bounds__(256) void lstm_prepack(
    const float* __restrict__ Wih, const float* __restrict__ Whh,
    const float* __restrict__ bih, const float* __restrict__ bhh,
    const float* __restrict__ Whr, const float* __restrict__ Wfc,
    const float* __restrict__ bfcin,
    unsigned short* __restrict__ gB, unsigned short* __restrict__ pB,
    unsigned short* __restrict__ fB, float* __restrict__ bsum,
    float* __restrict__ bfc, unsigned int* __restrict__ flags)
{
    int tid = blockIdx.x * 256 + threadIdx.x;

    if (tid < GFRAGS) {  // gates: cat(Wih, Whh) over K=256
        const int lane = tid & 63;
        int rest = tid >> 6;
        const int kt = rest & 7;   rest >>= 3;
        const int nt = rest & 127; rest >>= 7;
        const int l  = rest;
        const int n  = nt * 16 + (lane & 15);
        const int kb = kt * 32 + (lane >> 4) * 8;
        const float* src = (kb < 128)
            ? (Wih + ((size_t)l * NG + n) * PROJ + kb)
            : (Whh + ((size_t)l * NG + n) * PROJ + (kb - 128));
        unsigned short o[8];
        #pragma unroll
        for (int e = 0; e < 8; ++e) o[e] = f2b(src[e]);
        *(s8v*)(gB + (size_t)tid * 8) = *(const s8v*)o;
        return;
    }
    tid -= GFRAGS;
    if (tid < PFRAGS) {  // proj: Whr (p x 512), B[k][p] = Whr[p][k]
        const int lane = tid & 63;
        int rest = tid >> 6;
        const int kt = rest & 15; rest >>= 4;
        const int nt = rest & 7;  rest >>= 3;
        const int l  = rest;
        const int n  = nt * 16 + (lane & 15);
        const int kb = kt * 32 + (lane >> 4) * 8;
        const float* src = Whr + ((size_t)l * PROJ + n) * HID + kb;
        unsigned short o[8];
        #pragma unroll
        for (int e = 0; e < 8; ++e) o[e] = f2b(src[e]);
        *(s8v*)(pB + (size_t)tid * 8) = *(const s8v*)o;
        return;
    }
    tid -= PFRAGS;
    if (tid < FFRAGS) {  // fc: Wfc (128x128)
        const int lane = tid & 63;
        int rest = tid >> 6;
        const int kt = rest & 3;
        const int nt = rest >> 2;
        const int n  = nt * 16 + (lane & 15);
        const int kb = kt * 32 + (lane >> 4) * 8;
        const float* src = Wfc + (size_t)n * PROJ + kb;
        unsigned short o[8];
        #pragma unroll
        for (int e = 0; e < 8; ++e) o[e] = f2b(src[e]);
        *(s8v*)(fB + (size_t)tid * 8) = *(const s8v*)o;
        return;
    }
    tid -= FFRAGS;
    if (tid < NLAYER * NG) { bsum[tid] = bih[tid] + bhh[tid]; return; }
    tid -= NLAYER * NG;
    if (tid < PROJ) { bfc[tid] = bfcin[tid]; return; }
    tid -= PROJ;
    if (tid < NFLAGS) { flags[tid] = 0u; return; }
}

// ---------------------------------------------------------------------------
// Main: 192 blocks x 512 threads. Unit = (layer l, 64-row chunk): 4 sub-WGs,
// 32 waves. Wave u = sub*8+w holds its gates weight slab in 128 VGPRs
// (loaded once). Proj is K-SPLIT: sub q computes fp32 partial sums over its
// own j-quarter (local k-slice, B slab 32 KB in LDS) -> NO h_full exchange.
// The only per-step communication is the 4 partial slabs pp[unit][s%4][sub]
// ([64][128] f32). Consumers reduce in-register: own unit (h_rec, step s-1),
// downstream unit (xt, step s). ONE counter incr + ONE spin block per step.
// Placement: blockIdx%8 = XCD; a unit's 4 subs land on one XCD.
// ---------------------------------------------------------------------------
__global__ __launch_bounds__(512) void lstm_main(
    const float* __restrict__ x,               // [512][512][128] fp32
    const unsigned short* __restrict__ gB,
    const unsigned short* __restrict__ pB,
    const unsigned short* __restrict__ fB,
    const float* __restrict__ bsum,            // [6][2048]
    const float* __restrict__ bfc,             // [128]
    unsigned int* __restrict__ ub,             // [48] step counters
    float* __restrict__ pp,                    // [48][4][4][8192] f32 partials
    float* __restrict__ out)                   // [512][32][128] fp32
{
    const int xcd  = blockIdx.x & 7;
    const int slot = blockIdx.x >> 3;      // 0..23
    const int uo   = slot >> 2;            // 0..5
    const int sub  = slot & 3;
    const int unit = xcd * 6 + uo;         // 0..47
    const int l    = unit >> 3;
    const int c    = unit & 7;
    const int bb   = c * BC;

    __shared__ __align__(16) unsigned short xcat[64][264];    // A=[xt | h_rec], K=256
    __shared__ __align__(16) unsigned short hfullA[64][136];  // own j-quarter h_full
    __shared__ __align__(16) unsigned short pslab[2048 * 8];  // 32 KB proj B (k-slice)

    const int tid  = threadIdx.x;
    const int lane = tid & 63;
    const int w    = tid >> 6;            // wave 0..7
    const int u    = sub * 8 + w;         // unit-wave 0..31
    const int mrow = lane & 15;
    const int kgrp = lane >> 4;

    for (int i = tid; i < 64 * 264; i += 512) ((unsigned short*)xcat)[i] = 0;

    const s8v* gfrag = (const s8v*)gB;
    const s8v* pfrag = (const s8v*)pB;
    const s8v* ffrag = (const s8v*)fB;

    // ---- persistent gates weights: 32 fragments = 128 VGPRs ----
    s8v wreg[4][8];
    #pragma unroll
    for (int g = 0; g < 4; ++g)
      #pragma unroll
      for (int kt = 0; kt < 8; ++kt)
        wreg[g][kt] = gfrag[(((size_t)l * 128 + g * 32 + u) * 8 + kt) * 64 + lane];

    float bias[4];
    #pragma unroll
    for (int g = 0; g < 4; ++g)
        bias[g] = bsum[l * NG + g * HID + u * 16 + mrow];

    // ---- proj B slab (own k-slice: all 128 p, k in [sub*128, sub*128+128)) ----
    for (int i = tid; i < 2048; i += 512) {
        const int nt = i >> 8, ktl = (i >> 6) & 3, ln = i & 63;
        ((s8v*)pslab)[i] = pfrag[(((size_t)l * 8 + nt) * 16 + sub * 4 + ktl) * 64 + ln];
    }

    f4v cst[4];
    #pragma unroll
    for (int mt = 0; mt < 4; ++mt) cst[mt] = (f4v){0.f, 0.f, 0.f, 0.f};

    __syncthreads();

    #pragma unroll 1
    for (int s = 0; s < TOTS; ++s) {
        // ---- one spin block per step ----
        if (tid == 0) {
            if (l > 0) spin_ge(&ub[unit - NCHUNK], 4u * (s + 1));   // upstream partials(s)
            if (s > 0) spin_ge(&ub[unit], 4u * s);                  // own partials(s-1)
            if (l < NLAYER - 1 && s >= RINGP)
                spin_ge(&ub[unit + NCHUNK], 4u * (s - RINGP + 1));  // ring reuse guard
        }
        __syncthreads();                                            // S1

        // ---- build xcat lower (xt) ----
        if (l == 0) {
            if (s < SEQT) {
                #pragma unroll
                for (int k = 0; k < 4; ++k) {
                    const int f = k * 512 + tid;                    // float4 idx in [64][128]
                    const int m = f >> 5, q4 = f & 31;
                    const float4 v = *(const float4*)(x + (((size_t)(bb + m)) * SEQT + s) * PROJ + q4 * 4);
                    unsigned short o[4];
                    o[0] = f2b(v.x); o[1] = f2b(v.y); o[2] = f2b(v.z); o[3] = f2b(v.w);
                    *(ull*)&xcat[m][q4 * 4] = *(const ull*)o;
                }
            } else if (s == SEQT) {
                #pragma unroll
                for (int k = 0; k < 4; ++k) {
                    const int f = k * 512 + tid;
                    *(ull*)&xcat[f >> 5][(f & 31) * 4] = 0ull;
                }
            }
        } else {
            const ull* bu = (const ull*)(pp + (((size_t)(unit - NCHUNK) * RINGP + (s & 3)) * 4) * PP_FLOATS);
            #pragma unroll
            for (int k = 0; k < 8; ++k) {
                const int f = k * 512 + tid;                        // ull idx in slab (4096)
                const ull q0 = ald(bu + f), q1 = ald(bu + 4096 + f);
                const ull q2 = ald(bu + 8192 + f), q3 = ald(bu + 12288 + f);
                float l0, h0, l1, h1, l2, h2, l3, h3;
                upk(q0, l0, h0); upk(q1, l1, h1); upk(q2, l2, h2); upk(q3, l3, h3);
                const float lo = (l0 + l1) + (l2 + l3);
                const float hi = (h0 + h1) + (h2 + h3);
                const int F = f * 2, m = F >> 7, col = F & 127;
                *(unsigned int*)&xcat[m][col] =
                    (unsigned int)f2b(lo) | ((unsigned int)f2b(hi) << 16);
            }
        }
        // ---- build xcat upper (h_rec from own partials(s-1)) ----
        if (s > 0) {
            const ull* bh = (const ull*)(pp + (((size_t)unit * RINGP + ((s - 1) & 3)) * 4) * PP_FLOATS);
            #pragma unroll
            for (int k = 0; k < 8; ++k) {
                const int f = k * 512 + tid;
                const ull q0 = ald(bh + f), q1 = ald(bh + 4096 + f);
                const ull q2 = ald(bh + 8192 + f), q3 = ald(bh + 12288 + f);
                float l0, h0, l1, h1, l2, h2, l3, h3;
                upk(q0, l0, h0); upk(q1, l1, h1); upk(q2, l2, h2); upk(q3, l3, h3);
                const float lo = (l0 + l1) + (l2 + l3);
                const float hi = (h0 + h1) + (h2 + h3);
                const int F = f * 2, m = F >> 7, col = F & 127;
                *(unsigned int*)&xcat[m][128 + col] =
                    (unsigned int)f2b(lo) | ((unsigned int)f2b(hi) << 16);
            }
        }
        __syncthreads();                                            // S2

        // ---- gates GEMM (weights in regs) + pointwise, mt-outer ----
        #pragma unroll
        for (int mt = 0; mt < 4; ++mt) {
            f4v a0 = (f4v){bias[0], bias[0], bias[0], bias[0]};
            f4v a1 = (f4v){bias[1], bias[1], bias[1], bias[1]};
            f4v a2 = (f4v){bias[2], bias[2], bias[2], bias[2]};
            f4v a3 = (f4v){bias[3], bias[3], bias[3], bias[3]};
            #pragma unroll
            for (int kt = 0; kt < 8; ++kt) {
                const s8v a = *(const s8v*)&xcat[mt * 16 + mrow][kt * 32 + kgrp * 8];
                a0 = mfma16(a, wreg[0][kt], a0);
                a1 = mfma16(a, wreg[1][kt], a1);
                a2 = mfma16(a, wreg[2][kt], a2);
                a3 = mfma16(a, wreg[3][kt], a3);
            }
            f4v cv = cst[mt];
            #pragma unroll
            for (int r = 0; r < 4; ++r) {
                const float cn = sigf(a1[r]) * cv[r] + sigf(a0[r]) * tanh_fast(a2[r]);
                const float hf = sigf(a3[r]) * tanh_fast(cn);
                cv[r] = cn;
                hfullA[mt * 16 + kgrp * 4 + r][w * 16 + mrow] = f2b(hf);  // local j col
            }
            cst[mt] = cv;
        }
        __syncthreads();                                            // S3

        // ---- proj GEMM, K-SPLIT (own 128 k's); wave w -> p-tile w, all 4 m-tiles ----
        {
            f4v pacc[4];
            #pragma unroll
            for (int mt = 0; mt < 4; ++mt) pacc[mt] = (f4v){0.f, 0.f, 0.f, 0.f};
            #pragma unroll
            for (int ktl = 0; ktl < 4; ++ktl) {
                const s8v bf = ((const s8v*)pslab)[(w * 4 + ktl) * 64 + lane];
                #pragma unroll
                for (int mt = 0; mt < 4; ++mt) {
                    const s8v a = *(const s8v*)&hfullA[mt * 16 + mrow][ktl * 32 + kgrp * 8];
                    pacc[mt] = mfma16(a, bf, pacc[mt]);
                }
            }
            float* dst = pp + (((size_t)unit * RINGP + (s & 3)) * 4 + sub) * PP_FLOATS;
            #pragma unroll
            for (int mt = 0; mt < 4; ++mt)
                #pragma unroll
                for (int r = 0; r < 4; ++r)
                    astf(dst + (mt * 16 + kgrp * 4 + r) * 128 + w * 16 + mrow, pacc[mt][r]);
        }
        __syncthreads();                                            // S4 (drains stores)
        if (tid == 0)
            __hip_atomic_fetch_add(&ub[unit], 1u, __ATOMIC_RELEASE, __HIP_MEMORY_SCOPE_AGENT);

        // ---- FC head (decode, last layer): intra-unit round + reduce + GEMM ----
        if (l == NLAYER - 1 && s >= SEQT) {
            if (tid == 0) spin_ge(&ub[unit], 4u * (s + 1));
            __syncthreads();                                        // S5
            const ull* bh = (const ull*)(pp + (((size_t)unit * RINGP + (s & 3)) * 4) * PP_FLOATS);
            #pragma unroll
            for (int k = 0; k < 8; ++k) {
                const int f = k * 512 + tid;
                const ull q0 = ald(bh + f), q1 = ald(bh + 4096 + f);
                const ull q2 = ald(bh + 8192 + f), q3 = ald(bh + 12288 + f);
                float l0, h0, l1, h1, l2, h2, l3, h3;
                upk(q0, l0, h0); upk(q1, l1, h1); upk(q2, l2, h2); upk(q3, l3, h3);
                const float lo = sigf((l0 + l1) + (l2 + l3));
                const float hi = sigf((h0 + h1) + (h2 + h3));
                const int F = f * 2, m = F >> 7, col = F & 127;
                *(unsigned int*)&hfullA[m][col] =
                    (unsigned int)f2b(lo) | ((unsigned int)f2b(hi) << 16);
            }
            __syncthreads();                                        // S6
            const float bv = bfc[w * 16 + mrow];
            f4v facc[4];
            #pragma unroll
            for (int mt = 0; mt < 4; ++mt) facc[mt] = (f4v){bv, bv, bv, bv};
            #pragma unroll
            for (int kt = 0; kt < 4; ++kt) {
                const s8v bf = ffrag[((size_t)w * 4 + kt) * 64 + lane];
                #pragma unroll
                for (int mt = 0; mt < 4; ++mt) {
                    const s8v a = *(const s8v*)&hfullA[mt * 16 + mrow][kt * 32 + kgrp * 8];
                    facc[mt] = mfma16(a, bf, facc[mt]);
                }
            }
            const int td = s - SEQT;
            #pragma unroll
            for (int mt = 0; mt < 4; ++mt)
                #pragma unroll
                for (int r = 0; r < 4; ++r)
                    out[(((size_t)(bb + mt * 16 + kgrp * 4 + r)) * DSTEPS + td) * PROJ
                        + w * 16 + mrow] = facc[mt][r];
        }
    }
}

extern "C" void kernel_launch(void* const* d_in, const int* in_sizes, int n_in,
                              void* d_out, int out_size, void* d_ws, size_t ws_size,
                              hipStream_t stream)
{
    const float* x    = (const float*)d_in[0];
    const float* Wih  = (const float*)d_in[1];
    const float* Whh  = (const float*)d_in[2];
    const float* bih  = (const float*)d_in[3];
    const float* bhh  = (const float*)d_in[4];
    const float* Whr  = (const float*)d_in[5];
    const float* Wfc  = (const float*)d_in[6];
    const float* bfcv = (const float*)d_in[7];

    char* ws = (char*)d_ws;
    size_t off = 0;
    auto alloc = [&](size_t b) { char* p = ws + off; off += (b + 255) & ~(size_t)255; return p; };
    unsigned short* gB  = (unsigned short*)alloc((size_t)GFRAGS * 16);
    unsigned short* pB  = (unsigned short*)alloc((size_t)PFRAGS * 16);
    unsigned short* fB  = (unsigned short*)alloc((size_t)FFRAGS * 16);
    float* bsum         = (float*)alloc((size_t)NLAYER * NG * 4);
    float* bfc          = (float*)alloc((size_t)PROJ * 4);
    unsigned int* flags = (unsigned int*)alloc((size_t)NFLAGS * 4);
    float* pp           = (float*)alloc((size_t)NUNIT * RINGP * 4 * PP_FLOATS * 4);
    if (off > ws_size) return;  // workspace too small; fail validation cleanly

    const int total = GFRAGS + PFRAGS + FFRAGS + NLAYER * NG + PROJ + NFLAGS;
    lstm_prepack<<<(total + 255) / 256, 256, 0, stream>>>(
        Wih, Whh, bih, bhh, Whr, Wfc, bfcv, gB, pB, fB, bsum, bfc, flags);
    lstm_main<<<NUNIT * 4, 512, 0, stream>>>(
        x, gB, pB, fB, bsum, bfc, flags, pp, (float*)d_out);
}